// Round 7
// baseline (242.547 us; speedup 1.0000x reference)
//
#include <hip/hip_runtime.h>
#include <hip/hip_bf16.h>

#define BB 16
#define NN 1024
#define DD 5
#define RH 8
#define CAP 128

typedef unsigned long long u64;
typedef unsigned int u32;
typedef __hip_bfloat16 bf16;

static __device__ __forceinline__ float tof(bf16 x) { return __bfloat162float(x); }
// runtime-dtype load: f32 storage if f==true else bf16
static __device__ __forceinline__ float ldf(const void* p, long long i, bool f) {
  return f ? ((const float*)p)[i] : tof(((const bf16*)p)[i]);
}

#define LOG2E 1.4426950408889634f
#define PACK_BLOCKS (BB * NN * 16 / 256)  // 1024
#define KV_BLOCKS (BB * NN / 256)         // 64

// Round 19: attribution + cheapen the head. r6 taught: dur tracks BLOCK COUNT
// through the fused serial head (1024 blk -> 66-70us, 2048 blk -> 82us twice);
// j-split duplicated the head and lost. Totals obey ~121us fixed + sum(kernels)
// -> to win, a phase must get CHEAPER, not just move. This round:
//  - 3 kernels for per-phase visibility in top-5.
//  - k_twohop rewritten: LDS-staged bitset quarters (32KB coalesced stages,
//    pad-17 conflict-free LDS gather) instead of ~41MB random 128B L2 reads.
//    Lists built once/row, CAP=128 + correct global fallback via LDS atomicOr.
//  - k_attn lean: reads neighbits (coalesced), r5 shape (1024x512, 2 rows/wave),
//    r6's conflict-free plane/slot staging, atomic pool + last-block MLP.
//  Pre-committed: lean attn >=60 -> j-loop is the invariant (attack loop next);
//  twohop >=20 -> LDS-bitset theory wrong.

// ---------------------------------------------------------------- pack + kv
__global__ __launch_bounds__(256) void k_pack(
    const void* __restrict__ adj, const void* __restrict__ feats,
    const void* __restrict__ coors,
    const void* __restrict__ Wk, const void* __restrict__ Wv,
    const void* __restrict__ Wo,
    u64* __restrict__ adjbits, float4* __restrict__ kvg,
    float* __restrict__ czg, int* __restrict__ gflags,
    float* __restrict__ pooled, int* __restrict__ cntr) {
  __shared__ int sNon01, sNonpair, sLow3;
  __shared__ int sCnt[4];
  __shared__ float wkL[25], wvL[25], woL[25];
  int tid = threadIdx.x;

  if (blockIdx.x >= PACK_BLOCKS) {
    // ---------------- kv precompute role ----------------
    int kb = blockIdx.x - PACK_BLOCKS;
    if (kb == 0) {
      // zero pooled accumulators + block counters (workspace poisoned
      // between iterations); kernel-end flush publishes downstream.
      if (tid < BB * DD) pooled[tid] = 0.0f;
      else if (tid < BB * DD + BB) cntr[tid - BB * DD] = 0;
    }
    {
      u32 x = ((const u32*)feats)[tid];
      u32 lo = x & 0xFFFFu;
      int e = (int)((lo >> 7) & 0xFFu);
      bool insane = !(lo == 0u || (e >= 90 && e <= 150));
      u64 m = __ballot(insane);
      if ((tid & 63) == 0) sCnt[tid >> 6] = (int)__popcll(m);
    }
    __syncthreads();
    bool f32 = (sCnt[0] + sCnt[1] + sCnt[2] + sCnt[3]) > 64;
    if (tid < 25) {
      wkL[tid] = ldf(Wk, tid, f32);
      wvL[tid] = ldf(Wv, tid, f32);
      woL[tid] = ldf(Wo, tid, f32);
    }
    if (kb == 0 && tid == 0) gflags[0] = f32 ? 1 : 0;
    __syncthreads();
    long long node = (long long)kb * 256 + tid;  // < BB*NN
    float f0 = ldf(feats, node * DD + 0, f32), f1 = ldf(feats, node * DD + 1, f32),
          f2 = ldf(feats, node * DD + 2, f32), f3 = ldf(feats, node * DD + 3, f32),
          f4 = ldf(feats, node * DD + 4, f32);
    float k[DD], tv[DD], v[DD];
    #pragma unroll
    for (int e = 0; e < DD; ++e) {
      k[e] = f0 * wkL[e] + f1 * wkL[5 + e] + f2 * wkL[10 + e] + f3 * wkL[15 + e] +
             f4 * wkL[20 + e];
      tv[e] = f0 * wvL[e] + f1 * wvL[5 + e] + f2 * wvL[10 + e] + f3 * wvL[15 + e] +
              f4 * wvL[20 + e];
    }
    #pragma unroll
    for (int e = 0; e < DD; ++e)
      v[e] = tv[0] * woL[e] + tv[1] * woL[5 + e] + tv[2] * woL[10 + e] +
             tv[3] * woL[15 + e] + tv[4] * woL[20 + e];
    float cx = ldf(coors, node * 3 + 0, f32);
    float cy = ldf(coors, node * 3 + 1, f32);
    float cz = ldf(coors, node * 3 + 2, f32);
    kvg[node * 3 + 0] = make_float4(k[0], k[1], k[2], k[3]);
    kvg[node * 3 + 1] = make_float4(k[4], v[0], v[1], v[2]);
    kvg[node * 3 + 2] = make_float4(v[3], v[4], cx, cy);
    czg[node] = cz;
    return;
  }

  // ---------------- adjacency pack role ----------------
  if (tid == 0) { sNon01 = 0; sNonpair = 0; sLow3 = 0; }
  __syncthreads();
  {
    const u32* aw = (const u32*)adj;
    int non01 = 0, nonpair = 0, low3 = 0;
    for (int i = tid; i < 4096; i += 256) {
      u32 x = aw[i];
      u32 lo = x & 0xFFFFu, hi = x >> 16;
      non01 |= (x > 1u);
      nonpair |= !((lo == 0u || lo == 0x3F80u) && (hi == 0u || hi == 0x3F80u));
      low3 |= (lo == 0x3F80u);
    }
    if (non01) atomicOr(&sNon01, 1);
    if (nonpair) atomicOr(&sNonpair, 1);
    if (low3) atomicOr(&sLow3, 1);
  }
  __syncthreads();
  // mode: 0=int32, 1=byte, 2=bf16, 3=f32
  int mode;
  if (!sNon01) mode = 0;
  else if (!sNonpair) mode = sLow3 ? 2 : 3;
  else mode = 1;

  int gid = blockIdx.x * 256 + tid;
  int w = gid & 15;
  long long row = gid >> 4;
  long long base = row * NN + (long long)w * 64;
  u64 bits = 0;
  if (mode == 3) {
    const uint4* p = (const uint4*)((const float*)adj + base);
    #pragma unroll
    for (int t = 0; t < 16; ++t) {
      uint4 x = p[t];
      if (x.x << 1) bits |= 1ull << (4 * t + 0);   // ignore -0.0
      if (x.y << 1) bits |= 1ull << (4 * t + 1);
      if (x.z << 1) bits |= 1ull << (4 * t + 2);
      if (x.w << 1) bits |= 1ull << (4 * t + 3);
    }
  } else if (mode == 0) {
    const uint4* p = (const uint4*)((const u32*)adj + base);
    #pragma unroll
    for (int t = 0; t < 16; ++t) {
      uint4 x = p[t];
      if (x.x) bits |= 1ull << (4 * t + 0);
      if (x.y) bits |= 1ull << (4 * t + 1);
      if (x.z) bits |= 1ull << (4 * t + 2);
      if (x.w) bits |= 1ull << (4 * t + 3);
    }
  } else if (mode == 2) {
    const uint4* p = (const uint4*)((const unsigned short*)adj + base);
    #pragma unroll
    for (int t = 0; t < 8; ++t) {
      uint4 x = p[t];
      u32 c[4] = {x.x, x.y, x.z, x.w};
      #pragma unroll
      for (int q = 0; q < 4; ++q) {
        if ((c[q] & 0x7FFFu)) bits |= 1ull << (8 * t + 2 * q + 0);
        if ((c[q] >> 16) & 0x7FFFu) bits |= 1ull << (8 * t + 2 * q + 1);
      }
    }
  } else {
    const uint4* p = (const uint4*)((const unsigned char*)adj + base);
    #pragma unroll
    for (int t = 0; t < 4; ++t) {
      uint4 x = p[t];
      u32 c[4] = {x.x, x.y, x.z, x.w};
      #pragma unroll
      for (int q = 0; q < 4; ++q)
        #pragma unroll
        for (int bb = 0; bb < 4; ++bb)
          if ((c[q] >> (8 * bb)) & 0xFFu) bits |= 1ull << (16 * t + 4 * q + bb);
    }
  }
  adjbits[gid] = bits;
}

// ------------------------------------------- two-hop via LDS-staged bitsets
__global__ __launch_bounds__(256) void k_twohop(const u64* __restrict__ adjbits,
                                                u64* __restrict__ neighbits) {
  __shared__ u64 adjL[256][17];                 // 34.8 KB quarter stage (pad 17)
  __shared__ unsigned short listL[4][16][CAP];  // 16 KB one-hop lists
  __shared__ unsigned short cntL[4][16];
  __shared__ u64 accL[64][16];                  // 8 KB two-hop accumulators
  int tid = threadIdx.x;
  int wv = tid >> 6, lane = tid & 63;
  int b = blockIdx.x >> 4, strip = blockIdx.x & 15;
  int rowbase = strip * 64;
  const u64* basep = adjbits + (size_t)b * NN * 16;

  // zero own wave's acc rows (wave-local -> in-order DS pipe, no barrier)
  for (int i = lane; i < 16 * 16; i += 64)
    accL[wv * 16 + (i >> 4)][i & 15] = 0;

  // build one-hop lists, 16 rows per wave, wave-synchronous
  int w16 = lane & 15;
  for (int rr = 0; rr < 16; ++rr) {
    int row = rowbase + wv * 16 + rr;
    u64 rw = basep[(size_t)row * 16 + w16];
    int cnt = 0;
    #pragma unroll
    for (int sw = 0; sw < 16; ++sw) {
      u64 bits = __shfl(rw, sw, 64);
      int mybit = (int)((bits >> lane) & 1ull);
      int pre = __popcll(bits & ((1ull << lane) - 1ull));
      if (mybit) {
        int idx = cnt + pre;
        if (idx < CAP) {
          listL[wv][rr][idx] = (unsigned short)(sw * 64 + lane);
        } else {  // cold overflow path: direct global gather into accL
          int j = sw * 64 + lane;
          for (int w2 = 0; w2 < 16; ++w2)
            atomicOr(&accL[wv * 16 + rr][w2], basep[(size_t)j * 16 + w2]);
        }
      }
      cnt += __popcll(bits);
    }
    if (lane == 0) cntL[wv][rr] = (unsigned short)(cnt < CAP ? cnt : CAP);
  }

  // four 256-row quarters of the adjacency staged through LDS
  int grp = lane >> 4;
  for (int q = 0; q < 4; ++q) {
    __syncthreads();  // prior gather done before adjL overwrite
    const u64* src = basep + (size_t)q * 256 * 16;
    for (int k = 0; k < 16; ++k) {
      int li = k * 256 + tid;
      adjL[li >> 4][li & 15] = src[li];  // coalesced
    }
    __syncthreads();
    for (int rr = 0; rr < 16; ++rr) {
      int cnt = cntL[wv][rr];
      u64 a = 0;
      for (int n = grp; n < cnt; n += 4) {
        int j = listL[wv][rr][n];
        if ((j >> 8) == q) a |= adjL[j & 255][w16];
      }
      a |= __shfl_xor(a, 16, 64);
      a |= __shfl_xor(a, 32, 64);
      if (lane < 16) accL[wv * 16 + rr][lane] |= a;
    }
  }

  // write out: adj | adj^2 | eye, 4 rows per pass (full-wave coalesced)
  for (int rr4 = 0; rr4 < 4; ++rr4) {
    int rl = rr4 * 4 + grp;            // local row within wave's 16
    int row = rowbase + wv * 16 + rl;
    u64 nb = accL[wv * 16 + rl][w16] | basep[(size_t)row * 16 + w16];
    if (w16 == (row >> 6)) nb |= 1ull << (row & 63);
    neighbits[((size_t)b * NN + row) * 16 + w16] = nb;
  }
}

// ---------------- lean attention + pool + last-block MLP
__global__ __launch_bounds__(512) void k_attn(
    const void* __restrict__ feats, const void* __restrict__ coors,
    const void* __restrict__ Wq,
    const void* __restrict__ wr1, const void* __restrict__ br1,
    const void* __restrict__ wr2, const void* __restrict__ br2,
    const float4* __restrict__ kvg, const float* __restrict__ czg,
    const int* __restrict__ gflags, const u64* __restrict__ neighbits,
    float* __restrict__ pooled, int* __restrict__ cntr,
    const void* __restrict__ w1, const void* __restrict__ b1,
    const void* __restrict__ w2, const void* __restrict__ b2,
    float* __restrict__ out) {
  __shared__ __align__(16) float4 kvT[2][3][64];  // 6 KB
  __shared__ float czT[2][64];                    // 512 B
  __shared__ u64 neighL[16][16];                  // 2 KB
  __shared__ float qL[16 * DD], ciL[16 * 3];
  __shared__ float wqL[25];
  __shared__ float wrL[3][RH];
  __shared__ float sConst[2];
  __shared__ int sFast, sLast;
  __shared__ float waveC[8][DD];
  __shared__ float pM[DD];
  __shared__ float hL[128];

  int bi = blockIdx.x;
  int b = bi >> 6, chunk = bi & 63;  // 64 chunks of 16 rows, full j range
  int tid = threadIdx.x;

  // issue tile-0 loads immediately; plane/slot -> conflict-free LDS writes
  const float4* kvb3 = kvg + (size_t)b * NN * 3;
  const float* czb = czg + (size_t)b * NN;
  bool ldkv = tid < 192;
  bool ldcz = (tid >= 192) && (tid < 256);
  int plane = tid >> 6, slot = tid & 63;
  float4 stg;
  float stgc;
  if (ldkv) stg = kvb3[slot * 3 + plane];
  else if (ldcz) stgc = czb[tid - 192];

  bool f32 = gflags[0] != 0;
  if (tid < 25) wqL[tid] = ldf(Wq, tid, f32);
  if (tid >= 64 && tid < 64 + RH) {
    int h = tid - 64;
    wrL[0][h] = ldf(wr1, h, f32);
    wrL[1][h] = ldf(br1, h, f32);
    wrL[2][h] = ldf(wr2, h, f32);
  }
  if (tid == 96) {
    float c = 0.0f;
    int ok = 1;
    #pragma unroll
    for (int h = 0; h < RH; ++h) {
      float w1h = ldf(wr1, h, f32);
      if (ldf(br1, h, f32) != 0.0f) ok = 0;
      if (w1h > 0.0f) c += w1h * ldf(wr2, h, f32);
    }
    sConst[0] = c * LOG2E;
    sConst[1] = ldf(br2, 0, f32) * LOG2E;
    sFast = ok;
  }
  // stage neighbor masks for this chunk's 16 rows (coalesced u64)
  if (tid >= 256 && tid < 512) {
    int t2 = tid - 256;
    neighL[t2 >> 4][t2 & 15] =
        neighbits[((size_t)(b * NN) + chunk * 16) * 16 + t2];
  }
  __syncthreads();
  int fast = sFast;
  // q (scaled) + ci for this chunk's 16 rows
  if (tid < 16) {
    long long row = (long long)b * NN + chunk * 16 + tid;
    float f0 = ldf(feats, row * DD + 0, f32), f1 = ldf(feats, row * DD + 1, f32),
          f2 = ldf(feats, row * DD + 2, f32), f3 = ldf(feats, row * DD + 3, f32),
          f4 = ldf(feats, row * DD + 4, f32);
    float qsc = fast ? (0.4472135954999579f * LOG2E) : 0.4472135954999579f;
    #pragma unroll
    for (int e = 0; e < DD; ++e)
      qL[tid * DD + e] = (f0 * wqL[e] + f1 * wqL[5 + e] + f2 * wqL[10 + e] +
                          f3 * wqL[15 + e] + f4 * wqL[20 + e]) * qsc;
    #pragma unroll
    for (int c = 0; c < 3; ++c)
      ciL[tid * 3 + c] = ldf(coors, row * 3 + c, f32);
  }

  // write tile 0 into buf 0 (waits entry loads); conflict-free
  if (ldkv) kvT[0][plane][slot] = stg;
  else if (ldcz) czT[0][tid - 192] = stgc;
  __syncthreads();  // buf0 + qL/ciL + neighL visible

  // ---- attention over full j range, double-buffered LDS tiles
  int g = tid >> 6, lane = tid & 63;
  float q[2][DD], ci[2][3], l[2], A[2][DD];
  #pragma unroll
  for (int r = 0; r < 2; ++r) {
    #pragma unroll
    for (int e = 0; e < DD; ++e) q[r][e] = qL[(g * 2 + r) * DD + e];
    #pragma unroll
    for (int c = 0; c < 3; ++c) ci[r][c] = ciL[(g * 2 + r) * 3 + c];
    l[r] = 0.0f;
    #pragma unroll
    for (int e = 0; e < DD; ++e) A[r][e] = 0.0f;
  }
  float Cf = sConst[0], br2f = sConst[1];
  int cur = 0;
  for (int t = 0; t < 16; ++t) {
    if (t < 15) {  // issue next tile (wait deferred to the LDS write)
      if (ldkv) stg = kvb3[((t + 1) * 64 + slot) * 3 + plane];
      else if (ldcz) stgc = czb[(t + 1) * 64 + (tid - 192)];
    }
    float4 ka = kvT[cur][0][lane];
    float4 kb = kvT[cur][1][lane];
    float4 kc = kvT[cur][2][lane];
    float jz = czT[cur][lane];
    float jx = kc.z, jy = kc.w;
    u64 nw[2];
    #pragma unroll
    for (int r = 0; r < 2; ++r) nw[r] = neighL[g * 2 + r][t];
    if (fast) {
      #pragma unroll
      for (int r = 0; r < 2; ++r) {
        float cx = jx - ci[r][0], cy = jy - ci[r][1], cz = jz - ci[r][2];
        float dist =
            __builtin_amdgcn_sqrtf(fmaf(cx, cx, fmaf(cy, cy, fmaf(cz, cz, 1e-8f))));
        float s = fmaf(q[r][0], ka.x, br2f);
        s = fmaf(q[r][1], ka.y, s);
        s = fmaf(q[r][2], ka.z, s);
        s = fmaf(q[r][3], ka.w, s);
        s = fmaf(q[r][4], kb.x, s);
        s = fmaf(Cf, dist, s);
        s = fminf(s, 126.0f);
        s = ((nw[r] >> lane) & 1ull) ? s : -150.0f;
        float p = __builtin_amdgcn_exp2f(s);
        l[r] += p;
        A[r][0] = fmaf(p, kb.y, A[r][0]);
        A[r][1] = fmaf(p, kb.z, A[r][1]);
        A[r][2] = fmaf(p, kb.w, A[r][2]);
        A[r][3] = fmaf(p, kc.x, A[r][3]);
        A[r][4] = fmaf(p, kc.y, A[r][4]);
      }
    } else {
      #pragma unroll
      for (int r = 0; r < 2; ++r) {
        float cx = jx - ci[r][0], cy = jy - ci[r][1], cz = jz - ci[r][2];
        float dist = sqrtf(fmaf(cx, cx, fmaf(cy, cy, fmaf(cz, cz, 1e-8f))));
        float rb = ldf(br2, 0, f32);
        #pragma unroll
        for (int h = 0; h < RH; ++h)
          rb += fmaxf(dist * wrL[0][h] + wrL[1][h], 0.0f) * wrL[2][h];
        float s = fmaf(q[r][0], ka.x, rb);
        s = fmaf(q[r][1], ka.y, s);
        s = fmaf(q[r][2], ka.z, s);
        s = fmaf(q[r][3], ka.w, s);
        s = fmaf(q[r][4], kb.x, s);
        s = fminf(s, 85.0f);
        s = ((nw[r] >> lane) & 1ull) ? s : -100.0f;
        float p = __expf(s);
        l[r] += p;
        A[r][0] = fmaf(p, kb.y, A[r][0]);
        A[r][1] = fmaf(p, kb.z, A[r][1]);
        A[r][2] = fmaf(p, kb.w, A[r][2]);
        A[r][3] = fmaf(p, kc.x, A[r][3]);
        A[r][4] = fmaf(p, kc.y, A[r][4]);
      }
    }
    if (t < 15) {
      if (ldkv) kvT[cur ^ 1][plane][slot] = stg;
      else if (ldcz) czT[cur ^ 1][tid - 192] = stgc;
    }
    __syncthreads();
    cur ^= 1;
  }
  #pragma unroll
  for (int msk = 1; msk < 64; msk <<= 1) {
    #pragma unroll
    for (int r = 0; r < 2; ++r) {
      l[r] += __shfl_xor(l[r], msk, 64);
      A[r][0] += __shfl_xor(A[r][0], msk, 64);
      A[r][1] += __shfl_xor(A[r][1], msk, 64);
      A[r][2] += __shfl_xor(A[r][2], msk, 64);
      A[r][3] += __shfl_xor(A[r][3], msk, 64);
      A[r][4] += __shfl_xor(A[r][4], msk, 64);
    }
  }

  // ---- per-row contribution -> block-partial pool
  if (lane == 0) {
    float cw[DD] = {0.f, 0.f, 0.f, 0.f, 0.f};
    #pragma unroll
    for (int r = 0; r < 2; ++r) {
      long long grow = (long long)b * NN + chunk * 16 + g * 2 + r;
      float inv = (l[r] > 0.0f) ? 1.0f / l[r] : 0.0f;
      #pragma unroll
      for (int e = 0; e < DD; ++e)
        cw[e] += ldf(feats, grow * DD + e, f32) + A[r][e] * inv;
    }
    #pragma unroll
    for (int e = 0; e < DD; ++e) waveC[g][e] = cw[e];
  }
  __syncthreads();
  if (tid < DD) {
    float s = waveC[0][tid] + waveC[1][tid] + waveC[2][tid] + waveC[3][tid] +
              waveC[4][tid] + waveC[5][tid] + waveC[6][tid] + waveC[7][tid];
    float old = atomicAdd(&pooled[b * DD + tid], s);  // device-scope, coherent
    asm volatile("" :: "v"(old));  // consume return -> add done before cnt
  }
  __syncthreads();  // vmcnt drain: all 5 pooled adds done before counter bump
  if (tid == 0) sLast = (atomicAdd(&cntr[b], 1) == 63) ? 1 : 0;
  __syncthreads();

  // ---- last block for this b runs the pooled MLP
  if (sLast) {
    if (tid < DD) {
      float pv = __hip_atomic_load(&pooled[b * DD + tid], __ATOMIC_RELAXED,
                                   __HIP_MEMORY_SCOPE_AGENT);
      pM[tid] = pv * (1.0f / 1024.0f);
    }
    __syncthreads();
    if (tid < 128) {
      float acc = ldf(b1, tid, f32);
      #pragma unroll
      for (int d = 0; d < DD; ++d)
        acc = fmaf(pM[d], ldf(w1, d * 128 + tid, f32), acc);
      hL[tid] = fmaxf(acc, 0.0f);
    }
    __syncthreads();
    if (tid < 3) {
      float s = ldf(b2, tid, f32);
      for (int j2 = 0; j2 < 128; ++j2)
        s = fmaf(hL[j2], ldf(w2, j2 * 3 + tid, f32), s);
      out[b * 3 + tid] = s;
    }
  }
}

// ---------------------------------------------------------------- launch
extern "C" void kernel_launch(void* const* d_in, const int* in_sizes, int n_in,
                              void* d_out, int out_size, void* d_ws, size_t ws_size,
                              hipStream_t stream) {
  const void* adj = d_in[2];
  float* out = (float*)d_out;

  char* w = (char*)d_ws;
  int* gflags = (int*)w;                               // 16 B
  float* pooled = (float*)(w + 64);                    // 320 B
  int* cntr = (int*)(w + 512);                         // 64 B
  const size_t MB2 = (size_t)BB * NN * 16 * sizeof(u64);  // 2 MiB
  u64* adjbits = (u64*)(w + 4096);
  u64* neighbits = (u64*)(w + 4096 + MB2);
  float4* kvg = (float4*)(w + 4096 + 2 * MB2);         // 768 KiB
  float* czg = (float*)(w + 4096 + 2 * MB2 + 786432);  // 64 KiB

  k_pack<<<PACK_BLOCKS + KV_BLOCKS, 256, 0, stream>>>(
      adj, d_in[0], d_in[1], d_in[4], d_in[5], d_in[6], adjbits, kvg, czg,
      gflags, pooled, cntr);
  k_twohop<<<BB * 16, 256, 0, stream>>>(adjbits, neighbits);
  k_attn<<<BB * 64, 512, 0, stream>>>(
      d_in[0], d_in[1], d_in[3], d_in[7], d_in[8], d_in[9], d_in[10], kvg, czg,
      gflags, neighbits, pooled, cntr, d_in[11], d_in[12], d_in[13], d_in[14],
      out);
}

// Round 8
// 184.139 us; speedup vs baseline: 1.3172x; 1.3172x over previous
//
#include <hip/hip_runtime.h>
#include <hip/hip_bf16.h>

#define BB 16
#define NN 1024
#define DD 5
#define RH 8

typedef unsigned long long u64;
typedef unsigned int u32;
typedef __hip_bfloat16 bf16;

static __device__ __forceinline__ float tof(bf16 x) { return __bfloat162float(x); }
// runtime-dtype load: f32 storage if f==true else bf16
static __device__ __forceinline__ float ldf(const void* p, long long i, bool f) {
  return f ? ((const float*)p)[i] : tof(((const bf16*)p)[i]);
}

#define LOG2E 1.4426950408889634f
#define PACK_BLOCKS (BB * NN * 16 / 256)  // 1024
#define KV_BLOCKS (BB * NN / 256)         // 64

// Round 20: r7's pre-committed read fired -- LDS-bitset twohop (81us, occ 10%)
// collapsed parallelism; theory wrong. But k_attn vanished from top-5: the
// lean attention (head removed) is ~27-40us, HALF of the fused 66us. So keep
// the split, revert k_twohop to the round-0 proven scattered design (4096
// blocks, wave-per-row, 16K waves hide the L2 gather latency; ~10us by
// round-0 budget arithmetic). One change this round.
//  k_pack, k_attn: byte-identical to r7.

// ---------------------------------------------------------------- pack + kv
__global__ __launch_bounds__(256) void k_pack(
    const void* __restrict__ adj, const void* __restrict__ feats,
    const void* __restrict__ coors,
    const void* __restrict__ Wk, const void* __restrict__ Wv,
    const void* __restrict__ Wo,
    u64* __restrict__ adjbits, float4* __restrict__ kvg,
    float* __restrict__ czg, int* __restrict__ gflags,
    float* __restrict__ pooled, int* __restrict__ cntr) {
  __shared__ int sNon01, sNonpair, sLow3;
  __shared__ int sCnt[4];
  __shared__ float wkL[25], wvL[25], woL[25];
  int tid = threadIdx.x;

  if (blockIdx.x >= PACK_BLOCKS) {
    // ---------------- kv precompute role ----------------
    int kb = blockIdx.x - PACK_BLOCKS;
    if (kb == 0) {
      // zero pooled accumulators + block counters (workspace poisoned
      // between iterations); kernel-end flush publishes downstream.
      if (tid < BB * DD) pooled[tid] = 0.0f;
      else if (tid < BB * DD + BB) cntr[tid - BB * DD] = 0;
    }
    {
      u32 x = ((const u32*)feats)[tid];
      u32 lo = x & 0xFFFFu;
      int e = (int)((lo >> 7) & 0xFFu);
      bool insane = !(lo == 0u || (e >= 90 && e <= 150));
      u64 m = __ballot(insane);
      if ((tid & 63) == 0) sCnt[tid >> 6] = (int)__popcll(m);
    }
    __syncthreads();
    bool f32 = (sCnt[0] + sCnt[1] + sCnt[2] + sCnt[3]) > 64;
    if (tid < 25) {
      wkL[tid] = ldf(Wk, tid, f32);
      wvL[tid] = ldf(Wv, tid, f32);
      woL[tid] = ldf(Wo, tid, f32);
    }
    if (kb == 0 && tid == 0) gflags[0] = f32 ? 1 : 0;
    __syncthreads();
    long long node = (long long)kb * 256 + tid;  // < BB*NN
    float f0 = ldf(feats, node * DD + 0, f32), f1 = ldf(feats, node * DD + 1, f32),
          f2 = ldf(feats, node * DD + 2, f32), f3 = ldf(feats, node * DD + 3, f32),
          f4 = ldf(feats, node * DD + 4, f32);
    float k[DD], tv[DD], v[DD];
    #pragma unroll
    for (int e = 0; e < DD; ++e) {
      k[e] = f0 * wkL[e] + f1 * wkL[5 + e] + f2 * wkL[10 + e] + f3 * wkL[15 + e] +
             f4 * wkL[20 + e];
      tv[e] = f0 * wvL[e] + f1 * wvL[5 + e] + f2 * wvL[10 + e] + f3 * wvL[15 + e] +
              f4 * wvL[20 + e];
    }
    #pragma unroll
    for (int e = 0; e < DD; ++e)
      v[e] = tv[0] * woL[e] + tv[1] * woL[5 + e] + tv[2] * woL[10 + e] +
             tv[3] * woL[15 + e] + tv[4] * woL[20 + e];
    float cx = ldf(coors, node * 3 + 0, f32);
    float cy = ldf(coors, node * 3 + 1, f32);
    float cz = ldf(coors, node * 3 + 2, f32);
    kvg[node * 3 + 0] = make_float4(k[0], k[1], k[2], k[3]);
    kvg[node * 3 + 1] = make_float4(k[4], v[0], v[1], v[2]);
    kvg[node * 3 + 2] = make_float4(v[3], v[4], cx, cy);
    czg[node] = cz;
    return;
  }

  // ---------------- adjacency pack role ----------------
  if (tid == 0) { sNon01 = 0; sNonpair = 0; sLow3 = 0; }
  __syncthreads();
  {
    const u32* aw = (const u32*)adj;
    int non01 = 0, nonpair = 0, low3 = 0;
    for (int i = tid; i < 4096; i += 256) {
      u32 x = aw[i];
      u32 lo = x & 0xFFFFu, hi = x >> 16;
      non01 |= (x > 1u);
      nonpair |= !((lo == 0u || lo == 0x3F80u) && (hi == 0u || hi == 0x3F80u));
      low3 |= (lo == 0x3F80u);
    }
    if (non01) atomicOr(&sNon01, 1);
    if (nonpair) atomicOr(&sNonpair, 1);
    if (low3) atomicOr(&sLow3, 1);
  }
  __syncthreads();
  // mode: 0=int32, 1=byte, 2=bf16, 3=f32
  int mode;
  if (!sNon01) mode = 0;
  else if (!sNonpair) mode = sLow3 ? 2 : 3;
  else mode = 1;

  int gid = blockIdx.x * 256 + tid;
  int w = gid & 15;
  long long row = gid >> 4;
  long long base = row * NN + (long long)w * 64;
  u64 bits = 0;
  if (mode == 3) {
    const uint4* p = (const uint4*)((const float*)adj + base);
    #pragma unroll
    for (int t = 0; t < 16; ++t) {
      uint4 x = p[t];
      if (x.x << 1) bits |= 1ull << (4 * t + 0);   // ignore -0.0
      if (x.y << 1) bits |= 1ull << (4 * t + 1);
      if (x.z << 1) bits |= 1ull << (4 * t + 2);
      if (x.w << 1) bits |= 1ull << (4 * t + 3);
    }
  } else if (mode == 0) {
    const uint4* p = (const uint4*)((const u32*)adj + base);
    #pragma unroll
    for (int t = 0; t < 16; ++t) {
      uint4 x = p[t];
      if (x.x) bits |= 1ull << (4 * t + 0);
      if (x.y) bits |= 1ull << (4 * t + 1);
      if (x.z) bits |= 1ull << (4 * t + 2);
      if (x.w) bits |= 1ull << (4 * t + 3);
    }
  } else if (mode == 2) {
    const uint4* p = (const uint4*)((const unsigned short*)adj + base);
    #pragma unroll
    for (int t = 0; t < 8; ++t) {
      uint4 x = p[t];
      u32 c[4] = {x.x, x.y, x.z, x.w};
      #pragma unroll
      for (int q = 0; q < 4; ++q) {
        if ((c[q] & 0x7FFFu)) bits |= 1ull << (8 * t + 2 * q + 0);
        if ((c[q] >> 16) & 0x7FFFu) bits |= 1ull << (8 * t + 2 * q + 1);
      }
    }
  } else {
    const uint4* p = (const uint4*)((const unsigned char*)adj + base);
    #pragma unroll
    for (int t = 0; t < 4; ++t) {
      uint4 x = p[t];
      u32 c[4] = {x.x, x.y, x.z, x.w};
      #pragma unroll
      for (int q = 0; q < 4; ++q)
        #pragma unroll
        for (int bb = 0; bb < 4; ++bb)
          if ((c[q] >> (8 * bb)) & 0xFFu) bits |= 1ull << (16 * t + 4 * q + bb);
    }
  }
  adjbits[gid] = bits;
}

// -------------------------------------------------------------- two-hop
// Round-0 proven design: 4096 blocks, wave-per-row, per-wave LDS list,
// 4-group scattered L2 gather, latency hidden by 16K waves.
__global__ __launch_bounds__(256) void k_twohop(const u64* __restrict__ adjbits,
                                                u64* __restrict__ neighbits) {
  __shared__ unsigned short listL[4][NN];
  int wave = threadIdx.x >> 6, lane = threadIdx.x & 63;
  int row = blockIdx.x * 4 + wave;
  int b = row >> 10;
  int i = row & (NN - 1);
  int w = lane & 15;
  const u64* rowp = adjbits + (size_t)row * 16;
  u64 rw = rowp[w];
  unsigned short* list = listL[wave];
  int cnt = 0;
  #pragma unroll
  for (int sw = 0; sw < 16; ++sw) {
    u64 bits = __shfl(rw, sw, 64);
    int mybit = (int)((bits >> lane) & 1ull);
    int pre = __popcll(bits & ((1ull << lane) - 1ull));
    if (mybit) list[cnt + pre] = (unsigned short)(sw * 64 + lane);
    cnt += __popcll(bits);
  }
  __syncthreads();
  u64 acc = rw;
  if (w == (i >> 6)) acc |= 1ull << (i & 63);
  int g = lane >> 4;
  const u64* basep = adjbits + (size_t)b * NN * 16;
  for (int n = g; n < cnt; n += 4) {
    int j = list[n];
    acc |= basep[(size_t)j * 16 + w];
  }
  acc |= __shfl_xor(acc, 16, 64);
  acc |= __shfl_xor(acc, 32, 64);
  if (lane < 16) neighbits[(size_t)row * 16 + lane] = acc;
}

// ---------------- lean attention + pool + last-block MLP
__global__ __launch_bounds__(512) void k_attn(
    const void* __restrict__ feats, const void* __restrict__ coors,
    const void* __restrict__ Wq,
    const void* __restrict__ wr1, const void* __restrict__ br1,
    const void* __restrict__ wr2, const void* __restrict__ br2,
    const float4* __restrict__ kvg, const float* __restrict__ czg,
    const int* __restrict__ gflags, const u64* __restrict__ neighbits,
    float* __restrict__ pooled, int* __restrict__ cntr,
    const void* __restrict__ w1, const void* __restrict__ b1,
    const void* __restrict__ w2, const void* __restrict__ b2,
    float* __restrict__ out) {
  __shared__ __align__(16) float4 kvT[2][3][64];  // 6 KB
  __shared__ float czT[2][64];                    // 512 B
  __shared__ u64 neighL[16][16];                  // 2 KB
  __shared__ float qL[16 * DD], ciL[16 * 3];
  __shared__ float wqL[25];
  __shared__ float wrL[3][RH];
  __shared__ float sConst[2];
  __shared__ int sFast, sLast;
  __shared__ float waveC[8][DD];
  __shared__ float pM[DD];
  __shared__ float hL[128];

  int bi = blockIdx.x;
  int b = bi >> 6, chunk = bi & 63;  // 64 chunks of 16 rows, full j range
  int tid = threadIdx.x;

  // issue tile-0 loads immediately; plane/slot -> conflict-free LDS writes
  const float4* kvb3 = kvg + (size_t)b * NN * 3;
  const float* czb = czg + (size_t)b * NN;
  bool ldkv = tid < 192;
  bool ldcz = (tid >= 192) && (tid < 256);
  int plane = tid >> 6, slot = tid & 63;
  float4 stg;
  float stgc;
  if (ldkv) stg = kvb3[slot * 3 + plane];
  else if (ldcz) stgc = czb[tid - 192];

  bool f32 = gflags[0] != 0;
  if (tid < 25) wqL[tid] = ldf(Wq, tid, f32);
  if (tid >= 64 && tid < 64 + RH) {
    int h = tid - 64;
    wrL[0][h] = ldf(wr1, h, f32);
    wrL[1][h] = ldf(br1, h, f32);
    wrL[2][h] = ldf(wr2, h, f32);
  }
  if (tid == 96) {
    float c = 0.0f;
    int ok = 1;
    #pragma unroll
    for (int h = 0; h < RH; ++h) {
      float w1h = ldf(wr1, h, f32);
      if (ldf(br1, h, f32) != 0.0f) ok = 0;
      if (w1h > 0.0f) c += w1h * ldf(wr2, h, f32);
    }
    sConst[0] = c * LOG2E;
    sConst[1] = ldf(br2, 0, f32) * LOG2E;
    sFast = ok;
  }
  // stage neighbor masks for this chunk's 16 rows (coalesced u64)
  if (tid >= 256 && tid < 512) {
    int t2 = tid - 256;
    neighL[t2 >> 4][t2 & 15] =
        neighbits[((size_t)(b * NN) + chunk * 16) * 16 + t2];
  }
  __syncthreads();
  int fast = sFast;
  // q (scaled) + ci for this chunk's 16 rows
  if (tid < 16) {
    long long row = (long long)b * NN + chunk * 16 + tid;
    float f0 = ldf(feats, row * DD + 0, f32), f1 = ldf(feats, row * DD + 1, f32),
          f2 = ldf(feats, row * DD + 2, f32), f3 = ldf(feats, row * DD + 3, f32),
          f4 = ldf(feats, row * DD + 4, f32);
    float qsc = fast ? (0.4472135954999579f * LOG2E) : 0.4472135954999579f;
    #pragma unroll
    for (int e = 0; e < DD; ++e)
      qL[tid * DD + e] = (f0 * wqL[e] + f1 * wqL[5 + e] + f2 * wqL[10 + e] +
                          f3 * wqL[15 + e] + f4 * wqL[20 + e]) * qsc;
    #pragma unroll
    for (int c = 0; c < 3; ++c)
      ciL[tid * 3 + c] = ldf(coors, row * 3 + c, f32);
  }

  // write tile 0 into buf 0 (waits entry loads); conflict-free
  if (ldkv) kvT[0][plane][slot] = stg;
  else if (ldcz) czT[0][tid - 192] = stgc;
  __syncthreads();  // buf0 + qL/ciL + neighL visible

  // ---- attention over full j range, double-buffered LDS tiles
  int g = tid >> 6, lane = tid & 63;
  float q[2][DD], ci[2][3], l[2], A[2][DD];
  #pragma unroll
  for (int r = 0; r < 2; ++r) {
    #pragma unroll
    for (int e = 0; e < DD; ++e) q[r][e] = qL[(g * 2 + r) * DD + e];
    #pragma unroll
    for (int c = 0; c < 3; ++c) ci[r][c] = ciL[(g * 2 + r) * 3 + c];
    l[r] = 0.0f;
    #pragma unroll
    for (int e = 0; e < DD; ++e) A[r][e] = 0.0f;
  }
  float Cf = sConst[0], br2f = sConst[1];
  int cur = 0;
  for (int t = 0; t < 16; ++t) {
    if (t < 15) {  // issue next tile (wait deferred to the LDS write)
      if (ldkv) stg = kvb3[((t + 1) * 64 + slot) * 3 + plane];
      else if (ldcz) stgc = czb[(t + 1) * 64 + (tid - 192)];
    }
    float4 ka = kvT[cur][0][lane];
    float4 kb = kvT[cur][1][lane];
    float4 kc = kvT[cur][2][lane];
    float jz = czT[cur][lane];
    float jx = kc.z, jy = kc.w;
    u64 nw[2];
    #pragma unroll
    for (int r = 0; r < 2; ++r) nw[r] = neighL[g * 2 + r][t];
    if (fast) {
      #pragma unroll
      for (int r = 0; r < 2; ++r) {
        float cx = jx - ci[r][0], cy = jy - ci[r][1], cz = jz - ci[r][2];
        float dist =
            __builtin_amdgcn_sqrtf(fmaf(cx, cx, fmaf(cy, cy, fmaf(cz, cz, 1e-8f))));
        float s = fmaf(q[r][0], ka.x, br2f);
        s = fmaf(q[r][1], ka.y, s);
        s = fmaf(q[r][2], ka.z, s);
        s = fmaf(q[r][3], ka.w, s);
        s = fmaf(q[r][4], kb.x, s);
        s = fmaf(Cf, dist, s);
        s = fminf(s, 126.0f);
        s = ((nw[r] >> lane) & 1ull) ? s : -150.0f;
        float p = __builtin_amdgcn_exp2f(s);
        l[r] += p;
        A[r][0] = fmaf(p, kb.y, A[r][0]);
        A[r][1] = fmaf(p, kb.z, A[r][1]);
        A[r][2] = fmaf(p, kb.w, A[r][2]);
        A[r][3] = fmaf(p, kc.x, A[r][3]);
        A[r][4] = fmaf(p, kc.y, A[r][4]);
      }
    } else {
      #pragma unroll
      for (int r = 0; r < 2; ++r) {
        float cx = jx - ci[r][0], cy = jy - ci[r][1], cz = jz - ci[r][2];
        float dist = sqrtf(fmaf(cx, cx, fmaf(cy, cy, fmaf(cz, cz, 1e-8f))));
        float rb = ldf(br2, 0, f32);
        #pragma unroll
        for (int h = 0; h < RH; ++h)
          rb += fmaxf(dist * wrL[0][h] + wrL[1][h], 0.0f) * wrL[2][h];
        float s = fmaf(q[r][0], ka.x, rb);
        s = fmaf(q[r][1], ka.y, s);
        s = fmaf(q[r][2], ka.z, s);
        s = fmaf(q[r][3], ka.w, s);
        s = fmaf(q[r][4], kb.x, s);
        s = fminf(s, 85.0f);
        s = ((nw[r] >> lane) & 1ull) ? s : -100.0f;
        float p = __expf(s);
        l[r] += p;
        A[r][0] = fmaf(p, kb.y, A[r][0]);
        A[r][1] = fmaf(p, kb.z, A[r][1]);
        A[r][2] = fmaf(p, kb.w, A[r][2]);
        A[r][3] = fmaf(p, kc.x, A[r][3]);
        A[r][4] = fmaf(p, kc.y, A[r][4]);
      }
    }
    if (t < 15) {
      if (ldkv) kvT[cur ^ 1][plane][slot] = stg;
      else if (ldcz) czT[cur ^ 1][tid - 192] = stgc;
    }
    __syncthreads();
    cur ^= 1;
  }
  #pragma unroll
  for (int msk = 1; msk < 64; msk <<= 1) {
    #pragma unroll
    for (int r = 0; r < 2; ++r) {
      l[r] += __shfl_xor(l[r], msk, 64);
      A[r][0] += __shfl_xor(A[r][0], msk, 64);
      A[r][1] += __shfl_xor(A[r][1], msk, 64);
      A[r][2] += __shfl_xor(A[r][2], msk, 64);
      A[r][3] += __shfl_xor(A[r][3], msk, 64);
      A[r][4] += __shfl_xor(A[r][4], msk, 64);
    }
  }

  // ---- per-row contribution -> block-partial pool
  if (lane == 0) {
    float cw[DD] = {0.f, 0.f, 0.f, 0.f, 0.f};
    #pragma unroll
    for (int r = 0; r < 2; ++r) {
      long long grow = (long long)b * NN + chunk * 16 + g * 2 + r;
      float inv = (l[r] > 0.0f) ? 1.0f / l[r] : 0.0f;
      #pragma unroll
      for (int e = 0; e < DD; ++e)
        cw[e] += ldf(feats, grow * DD + e, f32) + A[r][e] * inv;
    }
    #pragma unroll
    for (int e = 0; e < DD; ++e) waveC[g][e] = cw[e];
  }
  __syncthreads();
  if (tid < DD) {
    float s = waveC[0][tid] + waveC[1][tid] + waveC[2][tid] + waveC[3][tid] +
              waveC[4][tid] + waveC[5][tid] + waveC[6][tid] + waveC[7][tid];
    float old = atomicAdd(&pooled[b * DD + tid], s);  // device-scope, coherent
    asm volatile("" :: "v"(old));  // consume return -> add done before cnt
  }
  __syncthreads();  // vmcnt drain: all 5 pooled adds done before counter bump
  if (tid == 0) sLast = (atomicAdd(&cntr[b], 1) == 63) ? 1 : 0;
  __syncthreads();

  // ---- last block for this b runs the pooled MLP
  if (sLast) {
    if (tid < DD) {
      float pv = __hip_atomic_load(&pooled[b * DD + tid], __ATOMIC_RELAXED,
                                   __HIP_MEMORY_SCOPE_AGENT);
      pM[tid] = pv * (1.0f / 1024.0f);
    }
    __syncthreads();
    if (tid < 128) {
      float acc = ldf(b1, tid, f32);
      #pragma unroll
      for (int d = 0; d < DD; ++d)
        acc = fmaf(pM[d], ldf(w1, d * 128 + tid, f32), acc);
      hL[tid] = fmaxf(acc, 0.0f);
    }
    __syncthreads();
    if (tid < 3) {
      float s = ldf(b2, tid, f32);
      for (int j2 = 0; j2 < 128; ++j2)
        s = fmaf(hL[j2], ldf(w2, j2 * 3 + tid, f32), s);
      out[b * 3 + tid] = s;
    }
  }
}

// ---------------------------------------------------------------- launch
extern "C" void kernel_launch(void* const* d_in, const int* in_sizes, int n_in,
                              void* d_out, int out_size, void* d_ws, size_t ws_size,
                              hipStream_t stream) {
  const void* adj = d_in[2];
  float* out = (float*)d_out;

  char* w = (char*)d_ws;
  int* gflags = (int*)w;                               // 16 B
  float* pooled = (float*)(w + 64);                    // 320 B
  int* cntr = (int*)(w + 512);                         // 64 B
  const size_t MB2 = (size_t)BB * NN * 16 * sizeof(u64);  // 2 MiB
  u64* adjbits = (u64*)(w + 4096);
  u64* neighbits = (u64*)(w + 4096 + MB2);
  float4* kvg = (float4*)(w + 4096 + 2 * MB2);         // 768 KiB
  float* czg = (float*)(w + 4096 + 2 * MB2 + 786432);  // 64 KiB

  k_pack<<<PACK_BLOCKS + KV_BLOCKS, 256, 0, stream>>>(
      adj, d_in[0], d_in[1], d_in[4], d_in[5], d_in[6], adjbits, kvg, czg,
      gflags, pooled, cntr);
  k_twohop<<<BB * NN / 4, 256, 0, stream>>>(adjbits, neighbits);
  k_attn<<<BB * 64, 512, 0, stream>>>(
      d_in[0], d_in[1], d_in[3], d_in[7], d_in[8], d_in[9], d_in[10], kvg, czg,
      gflags, neighbits, pooled, cntr, d_in[11], d_in[12], d_in[13], d_in[14],
      out);
}

// Round 9
// 183.405 us; speedup vs baseline: 1.3225x; 1.0040x over previous
//
#include <hip/hip_runtime.h>
#include <hip/hip_bf16.h>

#define BB 16
#define NN 1024
#define DD 5
#define RH 8

typedef unsigned long long u64;
typedef unsigned int u32;
typedef __hip_bfloat16 bf16;

static __device__ __forceinline__ float tof(bf16 x) { return __bfloat162float(x); }
// runtime-dtype load: f32 storage if f==true else bf16
static __device__ __forceinline__ float ldf(const void* p, long long i, bool f) {
  return f ? ((const float*)p)[i] : tof(((const bf16*)p)[i]);
}

#define LOG2E 1.4426950408889634f
#define PACK_BLOCKS (BB * NN * 16 / 256)  // 1024
#define KV_BLOCKS (BB * NN / 256)         // 64

// Round 21: r8 WIN (184.1us; first beat of the 187.9 baseline). k_attn=50us
// is now the top kernel. Barrier-convoy model confirmed across rounds: time
// scales with TILE count (r0 half-j: 8 tiles ~40us; r8: 16 tiles ~50us), not
// pair count -- each j-tile iteration costs one block-wide barrier convoy
// (L2 load + compute + 8-wave reconvergence, ~3-5us/tile). VALU floor is
// ~5us. This round: DELETE the loop barriers. Whole per-batch kv is 52KB ->
// stage kv(48K SoA)+cz(4K)+masks(2K) in LDS ONCE (one barrier), then each
// wave streams its 16 tiles independently: zero barriers in the j-loop,
// cross-iteration ILP, contiguous conflict-free ds_read_b128, wave-uniform
// mask broadcasts. LDS ~55KB -> 2 blocks/CU -> 16 waves/CU (r1's footprint
// mistake was this PLUS the fused serial head at 4 waves; lean + 8 waves is
// the corrected cell). Pre-committed: if dur doesn't move, limiter is
// intra-wave dep-chain latency -> next lever is 4 rows/wave ILP.
//  k_pack, k_twohop: byte-identical to r8.

// ---------------------------------------------------------------- pack + kv
__global__ __launch_bounds__(256) void k_pack(
    const void* __restrict__ adj, const void* __restrict__ feats,
    const void* __restrict__ coors,
    const void* __restrict__ Wk, const void* __restrict__ Wv,
    const void* __restrict__ Wo,
    u64* __restrict__ adjbits, float4* __restrict__ kvg,
    float* __restrict__ czg, int* __restrict__ gflags,
    float* __restrict__ pooled, int* __restrict__ cntr) {
  __shared__ int sNon01, sNonpair, sLow3;
  __shared__ int sCnt[4];
  __shared__ float wkL[25], wvL[25], woL[25];
  int tid = threadIdx.x;

  if (blockIdx.x >= PACK_BLOCKS) {
    // ---------------- kv precompute role ----------------
    int kb = blockIdx.x - PACK_BLOCKS;
    if (kb == 0) {
      // zero pooled accumulators + block counters (workspace poisoned
      // between iterations); kernel-end flush publishes downstream.
      if (tid < BB * DD) pooled[tid] = 0.0f;
      else if (tid < BB * DD + BB) cntr[tid - BB * DD] = 0;
    }
    {
      u32 x = ((const u32*)feats)[tid];
      u32 lo = x & 0xFFFFu;
      int e = (int)((lo >> 7) & 0xFFu);
      bool insane = !(lo == 0u || (e >= 90 && e <= 150));
      u64 m = __ballot(insane);
      if ((tid & 63) == 0) sCnt[tid >> 6] = (int)__popcll(m);
    }
    __syncthreads();
    bool f32 = (sCnt[0] + sCnt[1] + sCnt[2] + sCnt[3]) > 64;
    if (tid < 25) {
      wkL[tid] = ldf(Wk, tid, f32);
      wvL[tid] = ldf(Wv, tid, f32);
      woL[tid] = ldf(Wo, tid, f32);
    }
    if (kb == 0 && tid == 0) gflags[0] = f32 ? 1 : 0;
    __syncthreads();
    long long node = (long long)kb * 256 + tid;  // < BB*NN
    float f0 = ldf(feats, node * DD + 0, f32), f1 = ldf(feats, node * DD + 1, f32),
          f2 = ldf(feats, node * DD + 2, f32), f3 = ldf(feats, node * DD + 3, f32),
          f4 = ldf(feats, node * DD + 4, f32);
    float k[DD], tv[DD], v[DD];
    #pragma unroll
    for (int e = 0; e < DD; ++e) {
      k[e] = f0 * wkL[e] + f1 * wkL[5 + e] + f2 * wkL[10 + e] + f3 * wkL[15 + e] +
             f4 * wkL[20 + e];
      tv[e] = f0 * wvL[e] + f1 * wvL[5 + e] + f2 * wvL[10 + e] + f3 * wvL[15 + e] +
              f4 * wvL[20 + e];
    }
    #pragma unroll
    for (int e = 0; e < DD; ++e)
      v[e] = tv[0] * woL[e] + tv[1] * woL[5 + e] + tv[2] * woL[10 + e] +
             tv[3] * woL[15 + e] + tv[4] * woL[20 + e];
    float cx = ldf(coors, node * 3 + 0, f32);
    float cy = ldf(coors, node * 3 + 1, f32);
    float cz = ldf(coors, node * 3 + 2, f32);
    kvg[node * 3 + 0] = make_float4(k[0], k[1], k[2], k[3]);
    kvg[node * 3 + 1] = make_float4(k[4], v[0], v[1], v[2]);
    kvg[node * 3 + 2] = make_float4(v[3], v[4], cx, cy);
    czg[node] = cz;
    return;
  }

  // ---------------- adjacency pack role ----------------
  if (tid == 0) { sNon01 = 0; sNonpair = 0; sLow3 = 0; }
  __syncthreads();
  {
    const u32* aw = (const u32*)adj;
    int non01 = 0, nonpair = 0, low3 = 0;
    for (int i = tid; i < 4096; i += 256) {
      u32 x = aw[i];
      u32 lo = x & 0xFFFFu, hi = x >> 16;
      non01 |= (x > 1u);
      nonpair |= !((lo == 0u || lo == 0x3F80u) && (hi == 0u || hi == 0x3F80u));
      low3 |= (lo == 0x3F80u);
    }
    if (non01) atomicOr(&sNon01, 1);
    if (nonpair) atomicOr(&sNonpair, 1);
    if (low3) atomicOr(&sLow3, 1);
  }
  __syncthreads();
  // mode: 0=int32, 1=byte, 2=bf16, 3=f32
  int mode;
  if (!sNon01) mode = 0;
  else if (!sNonpair) mode = sLow3 ? 2 : 3;
  else mode = 1;

  int gid = blockIdx.x * 256 + tid;
  int w = gid & 15;
  long long row = gid >> 4;
  long long base = row * NN + (long long)w * 64;
  u64 bits = 0;
  if (mode == 3) {
    const uint4* p = (const uint4*)((const float*)adj + base);
    #pragma unroll
    for (int t = 0; t < 16; ++t) {
      uint4 x = p[t];
      if (x.x << 1) bits |= 1ull << (4 * t + 0);   // ignore -0.0
      if (x.y << 1) bits |= 1ull << (4 * t + 1);
      if (x.z << 1) bits |= 1ull << (4 * t + 2);
      if (x.w << 1) bits |= 1ull << (4 * t + 3);
    }
  } else if (mode == 0) {
    const uint4* p = (const uint4*)((const u32*)adj + base);
    #pragma unroll
    for (int t = 0; t < 16; ++t) {
      uint4 x = p[t];
      if (x.x) bits |= 1ull << (4 * t + 0);
      if (x.y) bits |= 1ull << (4 * t + 1);
      if (x.z) bits |= 1ull << (4 * t + 2);
      if (x.w) bits |= 1ull << (4 * t + 3);
    }
  } else if (mode == 2) {
    const uint4* p = (const uint4*)((const unsigned short*)adj + base);
    #pragma unroll
    for (int t = 0; t < 8; ++t) {
      uint4 x = p[t];
      u32 c[4] = {x.x, x.y, x.z, x.w};
      #pragma unroll
      for (int q = 0; q < 4; ++q) {
        if ((c[q] & 0x7FFFu)) bits |= 1ull << (8 * t + 2 * q + 0);
        if ((c[q] >> 16) & 0x7FFFu) bits |= 1ull << (8 * t + 2 * q + 1);
      }
    }
  } else {
    const uint4* p = (const uint4*)((const unsigned char*)adj + base);
    #pragma unroll
    for (int t = 0; t < 4; ++t) {
      uint4 x = p[t];
      u32 c[4] = {x.x, x.y, x.z, x.w};
      #pragma unroll
      for (int q = 0; q < 4; ++q)
        #pragma unroll
        for (int bb = 0; bb < 4; ++bb)
          if ((c[q] >> (8 * bb)) & 0xFFu) bits |= 1ull << (16 * t + 4 * q + bb);
    }
  }
  adjbits[gid] = bits;
}

// -------------------------------------------------------------- two-hop
// Round-0 proven design: 4096 blocks, wave-per-row, per-wave LDS list,
// 4-group scattered L2 gather, latency hidden by 16K waves.
__global__ __launch_bounds__(256) void k_twohop(const u64* __restrict__ adjbits,
                                                u64* __restrict__ neighbits) {
  __shared__ unsigned short listL[4][NN];
  int wave = threadIdx.x >> 6, lane = threadIdx.x & 63;
  int row = blockIdx.x * 4 + wave;
  int b = row >> 10;
  int i = row & (NN - 1);
  int w = lane & 15;
  const u64* rowp = adjbits + (size_t)row * 16;
  u64 rw = rowp[w];
  unsigned short* list = listL[wave];
  int cnt = 0;
  #pragma unroll
  for (int sw = 0; sw < 16; ++sw) {
    u64 bits = __shfl(rw, sw, 64);
    int mybit = (int)((bits >> lane) & 1ull);
    int pre = __popcll(bits & ((1ull << lane) - 1ull));
    if (mybit) list[cnt + pre] = (unsigned short)(sw * 64 + lane);
    cnt += __popcll(bits);
  }
  __syncthreads();
  u64 acc = rw;
  if (w == (i >> 6)) acc |= 1ull << (i & 63);
  int g = lane >> 4;
  const u64* basep = adjbits + (size_t)b * NN * 16;
  for (int n = g; n < cnt; n += 4) {
    int j = list[n];
    acc |= basep[(size_t)j * 16 + w];
  }
  acc |= __shfl_xor(acc, 16, 64);
  acc |= __shfl_xor(acc, 32, 64);
  if (lane < 16) neighbits[(size_t)row * 16 + lane] = acc;
}

// ---------------- lean attention, barrier-free j-loop + pool + MLP
__global__ __launch_bounds__(512) void k_attn(
    const void* __restrict__ feats, const void* __restrict__ coors,
    const void* __restrict__ Wq,
    const void* __restrict__ wr1, const void* __restrict__ br1,
    const void* __restrict__ wr2, const void* __restrict__ br2,
    const float4* __restrict__ kvg, const float* __restrict__ czg,
    const int* __restrict__ gflags, const u64* __restrict__ neighbits,
    float* __restrict__ pooled, int* __restrict__ cntr,
    const void* __restrict__ w1, const void* __restrict__ b1,
    const void* __restrict__ w2, const void* __restrict__ b2,
    float* __restrict__ out) {
  __shared__ __align__(16) float4 kvS[3][NN];  // 48 KB SoA (whole batch)
  __shared__ float czL[NN];                    // 4 KB
  __shared__ u64 neighL[16][16];               // 2 KB
  __shared__ float qL[16 * DD], ciL[16 * 3];
  __shared__ float wqL[25];
  __shared__ float wrL[3][RH];
  __shared__ float sConst[2];
  __shared__ int sFast, sLast;
  __shared__ float waveC[8][DD];
  __shared__ float pM[DD];
  __shared__ float hL[128];

  int bi = blockIdx.x;
  int b = bi >> 6, chunk = bi & 63;  // 64 chunks of 16 rows, full j range
  int tid = threadIdx.x;

  // ---- stage the whole batch's kv/cz/masks into LDS (coalesced, once)
  const float4* kvb3 = kvg + (size_t)b * NN * 3;
  const float* czb = czg + (size_t)b * NN;
  for (int idx = tid; idx < 3 * NN; idx += 512) {
    float4 v = kvb3[idx];
    kvS[idx % 3][idx / 3] = v;
  }
  for (int idx = tid; idx < NN; idx += 512) czL[idx] = czb[idx];
  if (tid >= 256 && tid < 512) {
    int t2 = tid - 256;
    neighL[t2 >> 4][t2 & 15] =
        neighbits[((size_t)(b * NN) + chunk * 16) * 16 + t2];
  }

  bool f32 = gflags[0] != 0;
  if (tid < 25) wqL[tid] = ldf(Wq, tid, f32);
  if (tid >= 64 && tid < 64 + RH) {
    int h = tid - 64;
    wrL[0][h] = ldf(wr1, h, f32);
    wrL[1][h] = ldf(br1, h, f32);
    wrL[2][h] = ldf(wr2, h, f32);
  }
  if (tid == 96) {
    float c = 0.0f;
    int ok = 1;
    #pragma unroll
    for (int h = 0; h < RH; ++h) {
      float w1h = ldf(wr1, h, f32);
      if (ldf(br1, h, f32) != 0.0f) ok = 0;
      if (w1h > 0.0f) c += w1h * ldf(wr2, h, f32);
    }
    sConst[0] = c * LOG2E;
    sConst[1] = ldf(br2, 0, f32) * LOG2E;
    sFast = ok;
  }
  __syncthreads();
  int fast = sFast;
  // q (scaled) + ci for this chunk's 16 rows
  if (tid < 16) {
    long long row = (long long)b * NN + chunk * 16 + tid;
    float f0 = ldf(feats, row * DD + 0, f32), f1 = ldf(feats, row * DD + 1, f32),
          f2 = ldf(feats, row * DD + 2, f32), f3 = ldf(feats, row * DD + 3, f32),
          f4 = ldf(feats, row * DD + 4, f32);
    float qsc = fast ? (0.4472135954999579f * LOG2E) : 0.4472135954999579f;
    #pragma unroll
    for (int e = 0; e < DD; ++e)
      qL[tid * DD + e] = (f0 * wqL[e] + f1 * wqL[5 + e] + f2 * wqL[10 + e] +
                          f3 * wqL[15 + e] + f4 * wqL[20 + e]) * qsc;
    #pragma unroll
    for (int c = 0; c < 3; ++c)
      ciL[tid * 3 + c] = ldf(coors, row * 3 + c, f32);
  }
  __syncthreads();  // all LDS ready; last barrier in the kernel's hot path

  // ---- barrier-free attention: each wave streams 16 tiles independently
  int g = tid >> 6, lane = tid & 63;
  float q[2][DD], ci[2][3], l[2], A[2][DD];
  #pragma unroll
  for (int r = 0; r < 2; ++r) {
    #pragma unroll
    for (int e = 0; e < DD; ++e) q[r][e] = qL[(g * 2 + r) * DD + e];
    #pragma unroll
    for (int c = 0; c < 3; ++c) ci[r][c] = ciL[(g * 2 + r) * 3 + c];
    l[r] = 0.0f;
    #pragma unroll
    for (int e = 0; e < DD; ++e) A[r][e] = 0.0f;
  }
  float Cf = sConst[0], br2f = sConst[1];
  for (int t = 0; t < 16; ++t) {
    int j = t * 64 + lane;
    float4 ka = kvS[0][j];
    float4 kb = kvS[1][j];
    float4 kc = kvS[2][j];
    float jz = czL[j];
    float jx = kc.z, jy = kc.w;
    u64 nw[2];
    #pragma unroll
    for (int r = 0; r < 2; ++r) nw[r] = neighL[g * 2 + r][t];
    if (fast) {
      #pragma unroll
      for (int r = 0; r < 2; ++r) {
        float cx = jx - ci[r][0], cy = jy - ci[r][1], cz = jz - ci[r][2];
        float dist =
            __builtin_amdgcn_sqrtf(fmaf(cx, cx, fmaf(cy, cy, fmaf(cz, cz, 1e-8f))));
        float s = fmaf(q[r][0], ka.x, br2f);
        s = fmaf(q[r][1], ka.y, s);
        s = fmaf(q[r][2], ka.z, s);
        s = fmaf(q[r][3], ka.w, s);
        s = fmaf(q[r][4], kb.x, s);
        s = fmaf(Cf, dist, s);
        s = fminf(s, 126.0f);
        s = ((nw[r] >> lane) & 1ull) ? s : -150.0f;
        float p = __builtin_amdgcn_exp2f(s);
        l[r] += p;
        A[r][0] = fmaf(p, kb.y, A[r][0]);
        A[r][1] = fmaf(p, kb.z, A[r][1]);
        A[r][2] = fmaf(p, kb.w, A[r][2]);
        A[r][3] = fmaf(p, kc.x, A[r][3]);
        A[r][4] = fmaf(p, kc.y, A[r][4]);
      }
    } else {
      #pragma unroll
      for (int r = 0; r < 2; ++r) {
        float cx = jx - ci[r][0], cy = jy - ci[r][1], cz = jz - ci[r][2];
        float dist = sqrtf(fmaf(cx, cx, fmaf(cy, cy, fmaf(cz, cz, 1e-8f))));
        float rb = ldf(br2, 0, f32);
        #pragma unroll
        for (int h = 0; h < RH; ++h)
          rb += fmaxf(dist * wrL[0][h] + wrL[1][h], 0.0f) * wrL[2][h];
        float s = fmaf(q[r][0], ka.x, rb);
        s = fmaf(q[r][1], ka.y, s);
        s = fmaf(q[r][2], ka.z, s);
        s = fmaf(q[r][3], ka.w, s);
        s = fmaf(q[r][4], kb.x, s);
        s = fminf(s, 85.0f);
        s = ((nw[r] >> lane) & 1ull) ? s : -100.0f;
        float p = __expf(s);
        l[r] += p;
        A[r][0] = fmaf(p, kb.y, A[r][0]);
        A[r][1] = fmaf(p, kb.z, A[r][1]);
        A[r][2] = fmaf(p, kb.w, A[r][2]);
        A[r][3] = fmaf(p, kc.x, A[r][3]);
        A[r][4] = fmaf(p, kc.y, A[r][4]);
      }
    }
  }
  #pragma unroll
  for (int msk = 1; msk < 64; msk <<= 1) {
    #pragma unroll
    for (int r = 0; r < 2; ++r) {
      l[r] += __shfl_xor(l[r], msk, 64);
      A[r][0] += __shfl_xor(A[r][0], msk, 64);
      A[r][1] += __shfl_xor(A[r][1], msk, 64);
      A[r][2] += __shfl_xor(A[r][2], msk, 64);
      A[r][3] += __shfl_xor(A[r][3], msk, 64);
      A[r][4] += __shfl_xor(A[r][4], msk, 64);
    }
  }

  // ---- per-row contribution -> block-partial pool
  if (lane == 0) {
    float cw[DD] = {0.f, 0.f, 0.f, 0.f, 0.f};
    #pragma unroll
    for (int r = 0; r < 2; ++r) {
      long long grow = (long long)b * NN + chunk * 16 + g * 2 + r;
      float inv = (l[r] > 0.0f) ? 1.0f / l[r] : 0.0f;
      #pragma unroll
      for (int e = 0; e < DD; ++e)
        cw[e] += ldf(feats, grow * DD + e, f32) + A[r][e] * inv;
    }
    #pragma unroll
    for (int e = 0; e < DD; ++e) waveC[g][e] = cw[e];
  }
  __syncthreads();
  if (tid < DD) {
    float s = waveC[0][tid] + waveC[1][tid] + waveC[2][tid] + waveC[3][tid] +
              waveC[4][tid] + waveC[5][tid] + waveC[6][tid] + waveC[7][tid];
    float old = atomicAdd(&pooled[b * DD + tid], s);  // device-scope, coherent
    asm volatile("" :: "v"(old));  // consume return -> add done before cnt
  }
  __syncthreads();  // vmcnt drain: all 5 pooled adds done before counter bump
  if (tid == 0) sLast = (atomicAdd(&cntr[b], 1) == 63) ? 1 : 0;
  __syncthreads();

  // ---- last block for this b runs the pooled MLP
  if (sLast) {
    if (tid < DD) {
      float pv = __hip_atomic_load(&pooled[b * DD + tid], __ATOMIC_RELAXED,
                                   __HIP_MEMORY_SCOPE_AGENT);
      pM[tid] = pv * (1.0f / 1024.0f);
    }
    __syncthreads();
    if (tid < 128) {
      float acc = ldf(b1, tid, f32);
      #pragma unroll
      for (int d = 0; d < DD; ++d)
        acc = fmaf(pM[d], ldf(w1, d * 128 + tid, f32), acc);
      hL[tid] = fmaxf(acc, 0.0f);
    }
    __syncthreads();
    if (tid < 3) {
      float s = ldf(b2, tid, f32);
      for (int j2 = 0; j2 < 128; ++j2)
        s = fmaf(hL[j2], ldf(w2, j2 * 3 + tid, f32), s);
      out[b * 3 + tid] = s;
    }
  }
}

// ---------------------------------------------------------------- launch
extern "C" void kernel_launch(void* const* d_in, const int* in_sizes, int n_in,
                              void* d_out, int out_size, void* d_ws, size_t ws_size,
                              hipStream_t stream) {
  const void* adj = d_in[2];
  float* out = (float*)d_out;

  char* w = (char*)d_ws;
  int* gflags = (int*)w;                               // 16 B
  float* pooled = (float*)(w + 64);                    // 320 B
  int* cntr = (int*)(w + 512);                         // 64 B
  const size_t MB2 = (size_t)BB * NN * 16 * sizeof(u64);  // 2 MiB
  u64* adjbits = (u64*)(w + 4096);
  u64* neighbits = (u64*)(w + 4096 + MB2);
  float4* kvg = (float4*)(w + 4096 + 2 * MB2);         // 768 KiB
  float* czg = (float*)(w + 4096 + 2 * MB2 + 786432);  // 64 KiB

  k_pack<<<PACK_BLOCKS + KV_BLOCKS, 256, 0, stream>>>(
      adj, d_in[0], d_in[1], d_in[4], d_in[5], d_in[6], adjbits, kvg, czg,
      gflags, pooled, cntr);
  k_twohop<<<BB * NN / 4, 256, 0, stream>>>(adjbits, neighbits);
  k_attn<<<BB * 64, 512, 0, stream>>>(
      d_in[0], d_in[1], d_in[3], d_in[7], d_in[8], d_in[9], d_in[10], kvg, czg,
      gflags, neighbits, pooled, cntr, d_in[11], d_in[12], d_in[13], d_in[14],
      out);
}

// Round 10
// 181.174 us; speedup vs baseline: 1.3388x; 1.0123x over previous
//
#include <hip/hip_runtime.h>
#include <hip/hip_bf16.h>

#define BB 16
#define NN 1024
#define DD 5
#define RH 8

typedef unsigned long long u64;
typedef unsigned int u32;
typedef __hip_bfloat16 bf16;

static __device__ __forceinline__ float tof(bf16 x) { return __bfloat162float(x); }
// runtime-dtype load: f32 storage if f==true else bf16
static __device__ __forceinline__ float ldf(const void* p, long long i, bool f) {
  return f ? ((const float*)p)[i] : tof(((const bf16*)p)[i]);
}

#define LOG2E 1.4426950408889634f
#define PACK_BLOCKS (BB * NN * 16 / 256)  // 1024
#define KV_BLOCKS (BB * NN / 256)         // 64

// Round 22: r9 neutral (48.6 vs 50.1) -> barrier-convoy model falsified for
// the lean kernel; limiter is intra-wave dep-chain latency (8 waves/SIMD
// offered, still ~70% stall; VALU ~15us, DS-pipe ~15us, dur 48.6us). Also:
// r9's kvS[idx%3][idx/3] staging write = 786K bank conflicts (plane stride
// 4096 floats == 0 mod 32 banks -> 3 planes of a node share a bank; r8's
// plane/slot write had 0). This round, the pre-committed lever:
//  - 4 rows/wave ILP: 512-thr blocks own 32-row chunks (grid BB*32=512).
//    24 independent acc chains/wave; halves block count -> halves the 52KB
//    staging repetitions (32/batch) and tail atomics.
//  - padded SoA kvS (plane stride 1025 float4): write groups (node+plane)%8
//    spread uniformly -> near-0 conflicts, reads stay conflict-free,
//    global reads stay coalesced.
//  Pre-committed: k_attn >=45 -> ILP theory dead too; with ~121us fixed
//  harness cost and kernel sum near pipe floors, declare practical roofline.
//  k_pack, k_twohop: byte-identical to r8/r9.

// ---------------------------------------------------------------- pack + kv
__global__ __launch_bounds__(256) void k_pack(
    const void* __restrict__ adj, const void* __restrict__ feats,
    const void* __restrict__ coors,
    const void* __restrict__ Wk, const void* __restrict__ Wv,
    const void* __restrict__ Wo,
    u64* __restrict__ adjbits, float4* __restrict__ kvg,
    float* __restrict__ czg, int* __restrict__ gflags,
    float* __restrict__ pooled, int* __restrict__ cntr) {
  __shared__ int sNon01, sNonpair, sLow3;
  __shared__ int sCnt[4];
  __shared__ float wkL[25], wvL[25], woL[25];
  int tid = threadIdx.x;

  if (blockIdx.x >= PACK_BLOCKS) {
    // ---------------- kv precompute role ----------------
    int kb = blockIdx.x - PACK_BLOCKS;
    if (kb == 0) {
      // zero pooled accumulators + block counters (workspace poisoned
      // between iterations); kernel-end flush publishes downstream.
      if (tid < BB * DD) pooled[tid] = 0.0f;
      else if (tid < BB * DD + BB) cntr[tid - BB * DD] = 0;
    }
    {
      u32 x = ((const u32*)feats)[tid];
      u32 lo = x & 0xFFFFu;
      int e = (int)((lo >> 7) & 0xFFu);
      bool insane = !(lo == 0u || (e >= 90 && e <= 150));
      u64 m = __ballot(insane);
      if ((tid & 63) == 0) sCnt[tid >> 6] = (int)__popcll(m);
    }
    __syncthreads();
    bool f32 = (sCnt[0] + sCnt[1] + sCnt[2] + sCnt[3]) > 64;
    if (tid < 25) {
      wkL[tid] = ldf(Wk, tid, f32);
      wvL[tid] = ldf(Wv, tid, f32);
      woL[tid] = ldf(Wo, tid, f32);
    }
    if (kb == 0 && tid == 0) gflags[0] = f32 ? 1 : 0;
    __syncthreads();
    long long node = (long long)kb * 256 + tid;  // < BB*NN
    float f0 = ldf(feats, node * DD + 0, f32), f1 = ldf(feats, node * DD + 1, f32),
          f2 = ldf(feats, node * DD + 2, f32), f3 = ldf(feats, node * DD + 3, f32),
          f4 = ldf(feats, node * DD + 4, f32);
    float k[DD], tv[DD], v[DD];
    #pragma unroll
    for (int e = 0; e < DD; ++e) {
      k[e] = f0 * wkL[e] + f1 * wkL[5 + e] + f2 * wkL[10 + e] + f3 * wkL[15 + e] +
             f4 * wkL[20 + e];
      tv[e] = f0 * wvL[e] + f1 * wvL[5 + e] + f2 * wvL[10 + e] + f3 * wvL[15 + e] +
              f4 * wvL[20 + e];
    }
    #pragma unroll
    for (int e = 0; e < DD; ++e)
      v[e] = tv[0] * woL[e] + tv[1] * woL[5 + e] + tv[2] * woL[10 + e] +
             tv[3] * woL[15 + e] + tv[4] * woL[20 + e];
    float cx = ldf(coors, node * 3 + 0, f32);
    float cy = ldf(coors, node * 3 + 1, f32);
    float cz = ldf(coors, node * 3 + 2, f32);
    kvg[node * 3 + 0] = make_float4(k[0], k[1], k[2], k[3]);
    kvg[node * 3 + 1] = make_float4(k[4], v[0], v[1], v[2]);
    kvg[node * 3 + 2] = make_float4(v[3], v[4], cx, cy);
    czg[node] = cz;
    return;
  }

  // ---------------- adjacency pack role ----------------
  if (tid == 0) { sNon01 = 0; sNonpair = 0; sLow3 = 0; }
  __syncthreads();
  {
    const u32* aw = (const u32*)adj;
    int non01 = 0, nonpair = 0, low3 = 0;
    for (int i = tid; i < 4096; i += 256) {
      u32 x = aw[i];
      u32 lo = x & 0xFFFFu, hi = x >> 16;
      non01 |= (x > 1u);
      nonpair |= !((lo == 0u || lo == 0x3F80u) && (hi == 0u || hi == 0x3F80u));
      low3 |= (lo == 0x3F80u);
    }
    if (non01) atomicOr(&sNon01, 1);
    if (nonpair) atomicOr(&sNonpair, 1);
    if (low3) atomicOr(&sLow3, 1);
  }
  __syncthreads();
  // mode: 0=int32, 1=byte, 2=bf16, 3=f32
  int mode;
  if (!sNon01) mode = 0;
  else if (!sNonpair) mode = sLow3 ? 2 : 3;
  else mode = 1;

  int gid = blockIdx.x * 256 + tid;
  int w = gid & 15;
  long long row = gid >> 4;
  long long base = row * NN + (long long)w * 64;
  u64 bits = 0;
  if (mode == 3) {
    const uint4* p = (const uint4*)((const float*)adj + base);
    #pragma unroll
    for (int t = 0; t < 16; ++t) {
      uint4 x = p[t];
      if (x.x << 1) bits |= 1ull << (4 * t + 0);   // ignore -0.0
      if (x.y << 1) bits |= 1ull << (4 * t + 1);
      if (x.z << 1) bits |= 1ull << (4 * t + 2);
      if (x.w << 1) bits |= 1ull << (4 * t + 3);
    }
  } else if (mode == 0) {
    const uint4* p = (const uint4*)((const u32*)adj + base);
    #pragma unroll
    for (int t = 0; t < 16; ++t) {
      uint4 x = p[t];
      if (x.x) bits |= 1ull << (4 * t + 0);
      if (x.y) bits |= 1ull << (4 * t + 1);
      if (x.z) bits |= 1ull << (4 * t + 2);
      if (x.w) bits |= 1ull << (4 * t + 3);
    }
  } else if (mode == 2) {
    const uint4* p = (const uint4*)((const unsigned short*)adj + base);
    #pragma unroll
    for (int t = 0; t < 8; ++t) {
      uint4 x = p[t];
      u32 c[4] = {x.x, x.y, x.z, x.w};
      #pragma unroll
      for (int q = 0; q < 4; ++q) {
        if ((c[q] & 0x7FFFu)) bits |= 1ull << (8 * t + 2 * q + 0);
        if ((c[q] >> 16) & 0x7FFFu) bits |= 1ull << (8 * t + 2 * q + 1);
      }
    }
  } else {
    const uint4* p = (const uint4*)((const unsigned char*)adj + base);
    #pragma unroll
    for (int t = 0; t < 4; ++t) {
      uint4 x = p[t];
      u32 c[4] = {x.x, x.y, x.z, x.w};
      #pragma unroll
      for (int q = 0; q < 4; ++q)
        #pragma unroll
        for (int bb = 0; bb < 4; ++bb)
          if ((c[q] >> (8 * bb)) & 0xFFu) bits |= 1ull << (16 * t + 4 * q + bb);
    }
  }
  adjbits[gid] = bits;
}

// -------------------------------------------------------------- two-hop
// Round-0 proven design: 4096 blocks, wave-per-row, per-wave LDS list,
// 4-group scattered L2 gather, latency hidden by 16K waves.
__global__ __launch_bounds__(256) void k_twohop(const u64* __restrict__ adjbits,
                                                u64* __restrict__ neighbits) {
  __shared__ unsigned short listL[4][NN];
  int wave = threadIdx.x >> 6, lane = threadIdx.x & 63;
  int row = blockIdx.x * 4 + wave;
  int b = row >> 10;
  int i = row & (NN - 1);
  int w = lane & 15;
  const u64* rowp = adjbits + (size_t)row * 16;
  u64 rw = rowp[w];
  unsigned short* list = listL[wave];
  int cnt = 0;
  #pragma unroll
  for (int sw = 0; sw < 16; ++sw) {
    u64 bits = __shfl(rw, sw, 64);
    int mybit = (int)((bits >> lane) & 1ull);
    int pre = __popcll(bits & ((1ull << lane) - 1ull));
    if (mybit) list[cnt + pre] = (unsigned short)(sw * 64 + lane);
    cnt += __popcll(bits);
  }
  __syncthreads();
  u64 acc = rw;
  if (w == (i >> 6)) acc |= 1ull << (i & 63);
  int g = lane >> 4;
  const u64* basep = adjbits + (size_t)b * NN * 16;
  for (int n = g; n < cnt; n += 4) {
    int j = list[n];
    acc |= basep[(size_t)j * 16 + w];
  }
  acc |= __shfl_xor(acc, 16, 64);
  acc |= __shfl_xor(acc, 32, 64);
  if (lane < 16) neighbits[(size_t)row * 16 + lane] = acc;
}

// ---------------- lean attention, 4 rows/wave, barrier-free j-loop
__global__ __launch_bounds__(512) void k_attn(
    const void* __restrict__ feats, const void* __restrict__ coors,
    const void* __restrict__ Wq,
    const void* __restrict__ wr1, const void* __restrict__ br1,
    const void* __restrict__ wr2, const void* __restrict__ br2,
    const float4* __restrict__ kvg, const float* __restrict__ czg,
    const int* __restrict__ gflags, const u64* __restrict__ neighbits,
    float* __restrict__ pooled, int* __restrict__ cntr,
    const void* __restrict__ w1, const void* __restrict__ b1,
    const void* __restrict__ w2, const void* __restrict__ b2,
    float* __restrict__ out) {
  __shared__ __align__(16) float4 kvS[3 * 1025];  // 49.2 KB padded SoA
  __shared__ float czL[NN];                       // 4 KB
  __shared__ u64 neighL[32][16];                  // 4 KB
  __shared__ float qL[32 * DD], ciL[32 * 3];
  __shared__ float wqL[25];
  __shared__ float wrL[3][RH];
  __shared__ float sConst[2];
  __shared__ int sFast, sLast;
  __shared__ float waveC[8][DD];
  __shared__ float pM[DD];
  __shared__ float hL[128];

  int bi = blockIdx.x;
  int b = bi >> 5, chunk = bi & 31;  // 32 chunks of 32 rows, full j range
  int tid = threadIdx.x;

  // ---- stage whole batch kv/cz + chunk masks into LDS (coalesced, once)
  const float4* kvb3 = kvg + (size_t)b * NN * 3;
  const float* czb = czg + (size_t)b * NN;
  for (int idx = tid; idx < 3 * NN; idx += 512) {
    float4 v = kvb3[idx];
    kvS[(idx % 3) * 1025 + idx / 3] = v;  // pad: plane stride 1025 -> ~no conflicts
  }
  for (int idx = tid; idx < NN; idx += 512) czL[idx] = czb[idx];
  {
    // 512 masks for 32 rows, one per thread, coalesced
    neighL[tid >> 4][tid & 15] =
        neighbits[((size_t)(b * NN) + chunk * 32) * 16 + tid];
  }

  bool f32 = gflags[0] != 0;
  if (tid < 25) wqL[tid] = ldf(Wq, tid, f32);
  if (tid >= 64 && tid < 64 + RH) {
    int h = tid - 64;
    wrL[0][h] = ldf(wr1, h, f32);
    wrL[1][h] = ldf(br1, h, f32);
    wrL[2][h] = ldf(wr2, h, f32);
  }
  if (tid == 96) {
    float c = 0.0f;
    int ok = 1;
    #pragma unroll
    for (int h = 0; h < RH; ++h) {
      float w1h = ldf(wr1, h, f32);
      if (ldf(br1, h, f32) != 0.0f) ok = 0;
      if (w1h > 0.0f) c += w1h * ldf(wr2, h, f32);
    }
    sConst[0] = c * LOG2E;
    sConst[1] = ldf(br2, 0, f32) * LOG2E;
    sFast = ok;
  }
  __syncthreads();
  int fast = sFast;
  // q (scaled) + ci for this chunk's 32 rows
  if (tid < 32) {
    long long row = (long long)b * NN + chunk * 32 + tid;
    float f0 = ldf(feats, row * DD + 0, f32), f1 = ldf(feats, row * DD + 1, f32),
          f2 = ldf(feats, row * DD + 2, f32), f3 = ldf(feats, row * DD + 3, f32),
          f4 = ldf(feats, row * DD + 4, f32);
    float qsc = fast ? (0.4472135954999579f * LOG2E) : 0.4472135954999579f;
    #pragma unroll
    for (int e = 0; e < DD; ++e)
      qL[tid * DD + e] = (f0 * wqL[e] + f1 * wqL[5 + e] + f2 * wqL[10 + e] +
                          f3 * wqL[15 + e] + f4 * wqL[20 + e]) * qsc;
    #pragma unroll
    for (int c = 0; c < 3; ++c)
      ciL[tid * 3 + c] = ldf(coors, row * 3 + c, f32);
  }
  __syncthreads();  // all LDS ready; last barrier before the j-loop

  // ---- barrier-free attention: each wave streams 16 tiles, 4 rows/wave
  int g = tid >> 6, lane = tid & 63;
  float q[4][DD], ci[4][3], l[4], A[4][DD];
  #pragma unroll
  for (int r = 0; r < 4; ++r) {
    #pragma unroll
    for (int e = 0; e < DD; ++e) q[r][e] = qL[(g * 4 + r) * DD + e];
    #pragma unroll
    for (int c = 0; c < 3; ++c) ci[r][c] = ciL[(g * 4 + r) * 3 + c];
    l[r] = 0.0f;
    #pragma unroll
    for (int e = 0; e < DD; ++e) A[r][e] = 0.0f;
  }
  float Cf = sConst[0], br2f = sConst[1];
  for (int t = 0; t < 16; ++t) {
    int j = t * 64 + lane;
    float4 ka = kvS[j];
    float4 kb = kvS[1025 + j];
    float4 kc = kvS[2050 + j];
    float jz = czL[j];
    float jx = kc.z, jy = kc.w;
    u64 nw[4];
    #pragma unroll
    for (int r = 0; r < 4; ++r) nw[r] = neighL[g * 4 + r][t];
    if (fast) {
      #pragma unroll
      for (int r = 0; r < 4; ++r) {
        float cx = jx - ci[r][0], cy = jy - ci[r][1], cz = jz - ci[r][2];
        float dist =
            __builtin_amdgcn_sqrtf(fmaf(cx, cx, fmaf(cy, cy, fmaf(cz, cz, 1e-8f))));
        float s = fmaf(q[r][0], ka.x, br2f);
        s = fmaf(q[r][1], ka.y, s);
        s = fmaf(q[r][2], ka.z, s);
        s = fmaf(q[r][3], ka.w, s);
        s = fmaf(q[r][4], kb.x, s);
        s = fmaf(Cf, dist, s);
        s = fminf(s, 126.0f);
        s = ((nw[r] >> lane) & 1ull) ? s : -150.0f;
        float p = __builtin_amdgcn_exp2f(s);
        l[r] += p;
        A[r][0] = fmaf(p, kb.y, A[r][0]);
        A[r][1] = fmaf(p, kb.z, A[r][1]);
        A[r][2] = fmaf(p, kb.w, A[r][2]);
        A[r][3] = fmaf(p, kc.x, A[r][3]);
        A[r][4] = fmaf(p, kc.y, A[r][4]);
      }
    } else {
      #pragma unroll
      for (int r = 0; r < 4; ++r) {
        float cx = jx - ci[r][0], cy = jy - ci[r][1], cz = jz - ci[r][2];
        float dist = sqrtf(fmaf(cx, cx, fmaf(cy, cy, fmaf(cz, cz, 1e-8f))));
        float rb = ldf(br2, 0, f32);
        #pragma unroll
        for (int h = 0; h < RH; ++h)
          rb += fmaxf(dist * wrL[0][h] + wrL[1][h], 0.0f) * wrL[2][h];
        float s = fmaf(q[r][0], ka.x, rb);
        s = fmaf(q[r][1], ka.y, s);
        s = fmaf(q[r][2], ka.z, s);
        s = fmaf(q[r][3], ka.w, s);
        s = fmaf(q[r][4], kb.x, s);
        s = fminf(s, 85.0f);
        s = ((nw[r] >> lane) & 1ull) ? s : -100.0f;
        float p = __expf(s);
        l[r] += p;
        A[r][0] = fmaf(p, kb.y, A[r][0]);
        A[r][1] = fmaf(p, kb.z, A[r][1]);
        A[r][2] = fmaf(p, kb.w, A[r][2]);
        A[r][3] = fmaf(p, kc.x, A[r][3]);
        A[r][4] = fmaf(p, kc.y, A[r][4]);
      }
    }
  }
  #pragma unroll
  for (int msk = 1; msk < 64; msk <<= 1) {
    #pragma unroll
    for (int r = 0; r < 4; ++r) {
      l[r] += __shfl_xor(l[r], msk, 64);
      A[r][0] += __shfl_xor(A[r][0], msk, 64);
      A[r][1] += __shfl_xor(A[r][1], msk, 64);
      A[r][2] += __shfl_xor(A[r][2], msk, 64);
      A[r][3] += __shfl_xor(A[r][3], msk, 64);
      A[r][4] += __shfl_xor(A[r][4], msk, 64);
    }
  }

  // ---- per-row contribution -> block-partial pool
  if (lane == 0) {
    float cw[DD] = {0.f, 0.f, 0.f, 0.f, 0.f};
    #pragma unroll
    for (int r = 0; r < 4; ++r) {
      long long grow = (long long)b * NN + chunk * 32 + g * 4 + r;
      float inv = (l[r] > 0.0f) ? 1.0f / l[r] : 0.0f;
      #pragma unroll
      for (int e = 0; e < DD; ++e)
        cw[e] += ldf(feats, grow * DD + e, f32) + A[r][e] * inv;
    }
    #pragma unroll
    for (int e = 0; e < DD; ++e) waveC[g][e] = cw[e];
  }
  __syncthreads();
  if (tid < DD) {
    float s = waveC[0][tid] + waveC[1][tid] + waveC[2][tid] + waveC[3][tid] +
              waveC[4][tid] + waveC[5][tid] + waveC[6][tid] + waveC[7][tid];
    float old = atomicAdd(&pooled[b * DD + tid], s);  // device-scope, coherent
    asm volatile("" :: "v"(old));  // consume return -> add done before cnt
  }
  __syncthreads();  // vmcnt drain: all 5 pooled adds done before counter bump
  if (tid == 0) sLast = (atomicAdd(&cntr[b], 1) == 31) ? 1 : 0;
  __syncthreads();

  // ---- last block for this b runs the pooled MLP
  if (sLast) {
    if (tid < DD) {
      float pv = __hip_atomic_load(&pooled[b * DD + tid], __ATOMIC_RELAXED,
                                   __HIP_MEMORY_SCOPE_AGENT);
      pM[tid] = pv * (1.0f / 1024.0f);
    }
    __syncthreads();
    if (tid < 128) {
      float acc = ldf(b1, tid, f32);
      #pragma unroll
      for (int d = 0; d < DD; ++d)
        acc = fmaf(pM[d], ldf(w1, d * 128 + tid, f32), acc);
      hL[tid] = fmaxf(acc, 0.0f);
    }
    __syncthreads();
    if (tid < 3) {
      float s = ldf(b2, tid, f32);
      for (int j2 = 0; j2 < 128; ++j2)
        s = fmaf(hL[j2], ldf(w2, j2 * 3 + tid, f32), s);
      out[b * 3 + tid] = s;
    }
  }
}

// ---------------------------------------------------------------- launch
extern "C" void kernel_launch(void* const* d_in, const int* in_sizes, int n_in,
                              void* d_out, int out_size, void* d_ws, size_t ws_size,
                              hipStream_t stream) {
  const void* adj = d_in[2];
  float* out = (float*)d_out;

  char* w = (char*)d_ws;
  int* gflags = (int*)w;                               // 16 B
  float* pooled = (float*)(w + 64);                    // 320 B
  int* cntr = (int*)(w + 512);                         // 64 B
  const size_t MB2 = (size_t)BB * NN * 16 * sizeof(u64);  // 2 MiB
  u64* adjbits = (u64*)(w + 4096);
  u64* neighbits = (u64*)(w + 4096 + MB2);
  float4* kvg = (float4*)(w + 4096 + 2 * MB2);         // 768 KiB
  float* czg = (float*)(w + 4096 + 2 * MB2 + 786432);  // 64 KiB

  k_pack<<<PACK_BLOCKS + KV_BLOCKS, 256, 0, stream>>>(
      adj, d_in[0], d_in[1], d_in[4], d_in[5], d_in[6], adjbits, kvg, czg,
      gflags, pooled, cntr);
  k_twohop<<<BB * NN / 4, 256, 0, stream>>>(adjbits, neighbits);
  k_attn<<<BB * 32, 512, 0, stream>>>(
      d_in[0], d_in[1], d_in[3], d_in[7], d_in[8], d_in[9], d_in[10], kvg, czg,
      gflags, neighbits, pooled, cntr, d_in[11], d_in[12], d_in[13], d_in[14],
      out);
}

// Round 11
// 174.623 us; speedup vs baseline: 1.3890x; 1.0375x over previous
//
#include <hip/hip_runtime.h>
#include <hip/hip_bf16.h>

#define BB 16
#define NN 1024
#define DD 5
#define RH 8

typedef unsigned long long u64;
typedef unsigned int u32;
typedef __hip_bfloat16 bf16;

static __device__ __forceinline__ float tof(bf16 x) { return __bfloat162float(x); }
// runtime-dtype load: f32 storage if f==true else bf16
static __device__ __forceinline__ float ldf(const void* p, long long i, bool f) {
  return f ? ((const float*)p)[i] : tof(((const bf16*)p)[i]);
}

#define LOG2E 1.4426950408889634f
#define PACK_BLOCKS (BB * NN * 16 / 256)  // 1024
#define KV_BLOCKS (BB * NN / 256)         // 64

// Round 23: r10 = 44.6us k_attn, occ 15% -> main phase is short (~5us/CU of
// issue); duration is ramp + THIN TAIL (2 blocks/CU exactly, 16 sLast blocks
// run a serial tid<3 x128 MLP loop while the machine idles) + exposed LDS
// latency. Conflicts only halved (pad spread groups, not lane-contiguity).
// Bundle of three non-loop fixes:
//  - staging writes node-per-thread, plane-contiguous (r8's 0-conflict
//    pattern); reads stay dense 48B/thread.
//  - MLP tail wave-parallel: 3 waves shuffle-reduce 128 products each
//    (replaces serial 128-iter loop on 3 threads).
//  - LDS->reg prefetch of tile t+1 in the barrier-free j-loop (hides ~120cy
//    LDS latency under ~200cy compute; +17 VGPR < 128 keeps 4 waves/SIMD).
//  Pre-committed: k_attn >= 40 -> residual irreducible here; declare
//  ROOFLINE next round (fixed ~136us harness floor dominates).
//  k_pack, k_twohop: byte-identical to r8/r9/r10.

// ---------------------------------------------------------------- pack + kv
__global__ __launch_bounds__(256) void k_pack(
    const void* __restrict__ adj, const void* __restrict__ feats,
    const void* __restrict__ coors,
    const void* __restrict__ Wk, const void* __restrict__ Wv,
    const void* __restrict__ Wo,
    u64* __restrict__ adjbits, float4* __restrict__ kvg,
    float* __restrict__ czg, int* __restrict__ gflags,
    float* __restrict__ pooled, int* __restrict__ cntr) {
  __shared__ int sNon01, sNonpair, sLow3;
  __shared__ int sCnt[4];
  __shared__ float wkL[25], wvL[25], woL[25];
  int tid = threadIdx.x;

  if (blockIdx.x >= PACK_BLOCKS) {
    // ---------------- kv precompute role ----------------
    int kb = blockIdx.x - PACK_BLOCKS;
    if (kb == 0) {
      // zero pooled accumulators + block counters (workspace poisoned
      // between iterations); kernel-end flush publishes downstream.
      if (tid < BB * DD) pooled[tid] = 0.0f;
      else if (tid < BB * DD + BB) cntr[tid - BB * DD] = 0;
    }
    {
      u32 x = ((const u32*)feats)[tid];
      u32 lo = x & 0xFFFFu;
      int e = (int)((lo >> 7) & 0xFFu);
      bool insane = !(lo == 0u || (e >= 90 && e <= 150));
      u64 m = __ballot(insane);
      if ((tid & 63) == 0) sCnt[tid >> 6] = (int)__popcll(m);
    }
    __syncthreads();
    bool f32 = (sCnt[0] + sCnt[1] + sCnt[2] + sCnt[3]) > 64;
    if (tid < 25) {
      wkL[tid] = ldf(Wk, tid, f32);
      wvL[tid] = ldf(Wv, tid, f32);
      woL[tid] = ldf(Wo, tid, f32);
    }
    if (kb == 0 && tid == 0) gflags[0] = f32 ? 1 : 0;
    __syncthreads();
    long long node = (long long)kb * 256 + tid;  // < BB*NN
    float f0 = ldf(feats, node * DD + 0, f32), f1 = ldf(feats, node * DD + 1, f32),
          f2 = ldf(feats, node * DD + 2, f32), f3 = ldf(feats, node * DD + 3, f32),
          f4 = ldf(feats, node * DD + 4, f32);
    float k[DD], tv[DD], v[DD];
    #pragma unroll
    for (int e = 0; e < DD; ++e) {
      k[e] = f0 * wkL[e] + f1 * wkL[5 + e] + f2 * wkL[10 + e] + f3 * wkL[15 + e] +
             f4 * wkL[20 + e];
      tv[e] = f0 * wvL[e] + f1 * wvL[5 + e] + f2 * wvL[10 + e] + f3 * wvL[15 + e] +
              f4 * wvL[20 + e];
    }
    #pragma unroll
    for (int e = 0; e < DD; ++e)
      v[e] = tv[0] * woL[e] + tv[1] * woL[5 + e] + tv[2] * woL[10 + e] +
             tv[3] * woL[15 + e] + tv[4] * woL[20 + e];
    float cx = ldf(coors, node * 3 + 0, f32);
    float cy = ldf(coors, node * 3 + 1, f32);
    float cz = ldf(coors, node * 3 + 2, f32);
    kvg[node * 3 + 0] = make_float4(k[0], k[1], k[2], k[3]);
    kvg[node * 3 + 1] = make_float4(k[4], v[0], v[1], v[2]);
    kvg[node * 3 + 2] = make_float4(v[3], v[4], cx, cy);
    czg[node] = cz;
    return;
  }

  // ---------------- adjacency pack role ----------------
  if (tid == 0) { sNon01 = 0; sNonpair = 0; sLow3 = 0; }
  __syncthreads();
  {
    const u32* aw = (const u32*)adj;
    int non01 = 0, nonpair = 0, low3 = 0;
    for (int i = tid; i < 4096; i += 256) {
      u32 x = aw[i];
      u32 lo = x & 0xFFFFu, hi = x >> 16;
      non01 |= (x > 1u);
      nonpair |= !((lo == 0u || lo == 0x3F80u) && (hi == 0u || hi == 0x3F80u));
      low3 |= (lo == 0x3F80u);
    }
    if (non01) atomicOr(&sNon01, 1);
    if (nonpair) atomicOr(&sNonpair, 1);
    if (low3) atomicOr(&sLow3, 1);
  }
  __syncthreads();
  // mode: 0=int32, 1=byte, 2=bf16, 3=f32
  int mode;
  if (!sNon01) mode = 0;
  else if (!sNonpair) mode = sLow3 ? 2 : 3;
  else mode = 1;

  int gid = blockIdx.x * 256 + tid;
  int w = gid & 15;
  long long row = gid >> 4;
  long long base = row * NN + (long long)w * 64;
  u64 bits = 0;
  if (mode == 3) {
    const uint4* p = (const uint4*)((const float*)adj + base);
    #pragma unroll
    for (int t = 0; t < 16; ++t) {
      uint4 x = p[t];
      if (x.x << 1) bits |= 1ull << (4 * t + 0);   // ignore -0.0
      if (x.y << 1) bits |= 1ull << (4 * t + 1);
      if (x.z << 1) bits |= 1ull << (4 * t + 2);
      if (x.w << 1) bits |= 1ull << (4 * t + 3);
    }
  } else if (mode == 0) {
    const uint4* p = (const uint4*)((const u32*)adj + base);
    #pragma unroll
    for (int t = 0; t < 16; ++t) {
      uint4 x = p[t];
      if (x.x) bits |= 1ull << (4 * t + 0);
      if (x.y) bits |= 1ull << (4 * t + 1);
      if (x.z) bits |= 1ull << (4 * t + 2);
      if (x.w) bits |= 1ull << (4 * t + 3);
    }
  } else if (mode == 2) {
    const uint4* p = (const uint4*)((const unsigned short*)adj + base);
    #pragma unroll
    for (int t = 0; t < 8; ++t) {
      uint4 x = p[t];
      u32 c[4] = {x.x, x.y, x.z, x.w};
      #pragma unroll
      for (int q = 0; q < 4; ++q) {
        if ((c[q] & 0x7FFFu)) bits |= 1ull << (8 * t + 2 * q + 0);
        if ((c[q] >> 16) & 0x7FFFu) bits |= 1ull << (8 * t + 2 * q + 1);
      }
    }
  } else {
    const uint4* p = (const uint4*)((const unsigned char*)adj + base);
    #pragma unroll
    for (int t = 0; t < 4; ++t) {
      uint4 x = p[t];
      u32 c[4] = {x.x, x.y, x.z, x.w};
      #pragma unroll
      for (int q = 0; q < 4; ++q)
        #pragma unroll
        for (int bb = 0; bb < 4; ++bb)
          if ((c[q] >> (8 * bb)) & 0xFFu) bits |= 1ull << (16 * t + 4 * q + bb);
    }
  }
  adjbits[gid] = bits;
}

// -------------------------------------------------------------- two-hop
// Round-0 proven design: 4096 blocks, wave-per-row, per-wave LDS list,
// 4-group scattered L2 gather, latency hidden by 16K waves.
__global__ __launch_bounds__(256) void k_twohop(const u64* __restrict__ adjbits,
                                                u64* __restrict__ neighbits) {
  __shared__ unsigned short listL[4][NN];
  int wave = threadIdx.x >> 6, lane = threadIdx.x & 63;
  int row = blockIdx.x * 4 + wave;
  int b = row >> 10;
  int i = row & (NN - 1);
  int w = lane & 15;
  const u64* rowp = adjbits + (size_t)row * 16;
  u64 rw = rowp[w];
  unsigned short* list = listL[wave];
  int cnt = 0;
  #pragma unroll
  for (int sw = 0; sw < 16; ++sw) {
    u64 bits = __shfl(rw, sw, 64);
    int mybit = (int)((bits >> lane) & 1ull);
    int pre = __popcll(bits & ((1ull << lane) - 1ull));
    if (mybit) list[cnt + pre] = (unsigned short)(sw * 64 + lane);
    cnt += __popcll(bits);
  }
  __syncthreads();
  u64 acc = rw;
  if (w == (i >> 6)) acc |= 1ull << (i & 63);
  int g = lane >> 4;
  const u64* basep = adjbits + (size_t)b * NN * 16;
  for (int n = g; n < cnt; n += 4) {
    int j = list[n];
    acc |= basep[(size_t)j * 16 + w];
  }
  acc |= __shfl_xor(acc, 16, 64);
  acc |= __shfl_xor(acc, 32, 64);
  if (lane < 16) neighbits[(size_t)row * 16 + lane] = acc;
}

// ---------------- lean attention, 4 rows/wave, barrier-free + reg prefetch
__global__ __launch_bounds__(512) void k_attn(
    const void* __restrict__ feats, const void* __restrict__ coors,
    const void* __restrict__ Wq,
    const void* __restrict__ wr1, const void* __restrict__ br1,
    const void* __restrict__ wr2, const void* __restrict__ br2,
    const float4* __restrict__ kvg, const float* __restrict__ czg,
    const int* __restrict__ gflags, const u64* __restrict__ neighbits,
    float* __restrict__ pooled, int* __restrict__ cntr,
    const void* __restrict__ w1, const void* __restrict__ b1,
    const void* __restrict__ w2, const void* __restrict__ b2,
    float* __restrict__ out) {
  __shared__ __align__(16) float4 kvS[3 * 1025];  // 49.2 KB padded SoA
  __shared__ float czL[NN];                       // 4 KB
  __shared__ u64 neighL[32][16];                  // 4 KB
  __shared__ float qL[32 * DD], ciL[32 * 3];
  __shared__ float wqL[25];
  __shared__ float wrL[3][RH];
  __shared__ float sConst[2];
  __shared__ int sFast, sLast;
  __shared__ float waveC[8][DD];
  __shared__ float pM[DD];
  __shared__ float hL[128];

  int bi = blockIdx.x;
  int b = bi >> 5, chunk = bi & 31;  // 32 chunks of 32 rows, full j range
  int tid = threadIdx.x;

  // ---- stage whole batch kv/cz + chunk masks into LDS (coalesced, once)
  // node-per-thread: per-plane writes are lane-contiguous -> 0 conflicts
  // (r8's proven pattern); reads are dense 48 B/thread.
  const float4* kvb3 = kvg + (size_t)b * NN * 3;
  const float* czb = czg + (size_t)b * NN;
  for (int node = tid; node < NN; node += 512) {
    float4 a = kvb3[node * 3 + 0];
    float4 bq = kvb3[node * 3 + 1];
    float4 c = kvb3[node * 3 + 2];
    kvS[node] = a;
    kvS[1025 + node] = bq;
    kvS[2050 + node] = c;
  }
  for (int idx = tid; idx < NN; idx += 512) czL[idx] = czb[idx];
  {
    // 512 masks for 32 rows, one per thread, coalesced
    neighL[tid >> 4][tid & 15] =
        neighbits[((size_t)(b * NN) + chunk * 32) * 16 + tid];
  }

  bool f32 = gflags[0] != 0;
  if (tid < 25) wqL[tid] = ldf(Wq, tid, f32);
  if (tid >= 64 && tid < 64 + RH) {
    int h = tid - 64;
    wrL[0][h] = ldf(wr1, h, f32);
    wrL[1][h] = ldf(br1, h, f32);
    wrL[2][h] = ldf(wr2, h, f32);
  }
  if (tid == 96) {
    float c = 0.0f;
    int ok = 1;
    #pragma unroll
    for (int h = 0; h < RH; ++h) {
      float w1h = ldf(wr1, h, f32);
      if (ldf(br1, h, f32) != 0.0f) ok = 0;
      if (w1h > 0.0f) c += w1h * ldf(wr2, h, f32);
    }
    sConst[0] = c * LOG2E;
    sConst[1] = ldf(br2, 0, f32) * LOG2E;
    sFast = ok;
  }
  __syncthreads();
  int fast = sFast;
  // q (scaled) + ci for this chunk's 32 rows
  if (tid < 32) {
    long long row = (long long)b * NN + chunk * 32 + tid;
    float f0 = ldf(feats, row * DD + 0, f32), f1 = ldf(feats, row * DD + 1, f32),
          f2 = ldf(feats, row * DD + 2, f32), f3 = ldf(feats, row * DD + 3, f32),
          f4 = ldf(feats, row * DD + 4, f32);
    float qsc = fast ? (0.4472135954999579f * LOG2E) : 0.4472135954999579f;
    #pragma unroll
    for (int e = 0; e < DD; ++e)
      qL[tid * DD + e] = (f0 * wqL[e] + f1 * wqL[5 + e] + f2 * wqL[10 + e] +
                          f3 * wqL[15 + e] + f4 * wqL[20 + e]) * qsc;
    #pragma unroll
    for (int c = 0; c < 3; ++c)
      ciL[tid * 3 + c] = ldf(coors, row * 3 + c, f32);
  }
  __syncthreads();  // all LDS ready; last barrier before the j-loop

  // ---- barrier-free attention: 16 tiles, 4 rows/wave, LDS->reg prefetch
  int g = tid >> 6, lane = tid & 63;
  float q[4][DD], ci[4][3], l[4], A[4][DD];
  #pragma unroll
  for (int r = 0; r < 4; ++r) {
    #pragma unroll
    for (int e = 0; e < DD; ++e) q[r][e] = qL[(g * 4 + r) * DD + e];
    #pragma unroll
    for (int c = 0; c < 3; ++c) ci[r][c] = ciL[(g * 4 + r) * 3 + c];
    l[r] = 0.0f;
    #pragma unroll
    for (int e = 0; e < DD; ++e) A[r][e] = 0.0f;
  }
  float Cf = sConst[0], br2f = sConst[1];
  float4 ka = kvS[lane];
  float4 kb = kvS[1025 + lane];
  float4 kc = kvS[2050 + lane];
  float jz = czL[lane];
  for (int t = 0; t < 16; ++t) {
    float4 nka, nkb, nkc;
    float njz;
    if (t < 15) {  // prefetch next tile from LDS while computing this one
      int nj = (t + 1) * 64 + lane;
      nka = kvS[nj];
      nkb = kvS[1025 + nj];
      nkc = kvS[2050 + nj];
      njz = czL[nj];
    }
    float jx = kc.z, jy = kc.w;
    u64 nw[4];
    #pragma unroll
    for (int r = 0; r < 4; ++r) nw[r] = neighL[g * 4 + r][t];
    if (fast) {
      #pragma unroll
      for (int r = 0; r < 4; ++r) {
        float cx = jx - ci[r][0], cy = jy - ci[r][1], cz = jz - ci[r][2];
        float dist =
            __builtin_amdgcn_sqrtf(fmaf(cx, cx, fmaf(cy, cy, fmaf(cz, cz, 1e-8f))));
        float s = fmaf(q[r][0], ka.x, br2f);
        s = fmaf(q[r][1], ka.y, s);
        s = fmaf(q[r][2], ka.z, s);
        s = fmaf(q[r][3], ka.w, s);
        s = fmaf(q[r][4], kb.x, s);
        s = fmaf(Cf, dist, s);
        s = fminf(s, 126.0f);
        s = ((nw[r] >> lane) & 1ull) ? s : -150.0f;
        float p = __builtin_amdgcn_exp2f(s);
        l[r] += p;
        A[r][0] = fmaf(p, kb.y, A[r][0]);
        A[r][1] = fmaf(p, kb.z, A[r][1]);
        A[r][2] = fmaf(p, kb.w, A[r][2]);
        A[r][3] = fmaf(p, kc.x, A[r][3]);
        A[r][4] = fmaf(p, kc.y, A[r][4]);
      }
    } else {
      #pragma unroll
      for (int r = 0; r < 4; ++r) {
        float cx = jx - ci[r][0], cy = jy - ci[r][1], cz = jz - ci[r][2];
        float dist = sqrtf(fmaf(cx, cx, fmaf(cy, cy, fmaf(cz, cz, 1e-8f))));
        float rb = ldf(br2, 0, f32);
        #pragma unroll
        for (int h = 0; h < RH; ++h)
          rb += fmaxf(dist * wrL[0][h] + wrL[1][h], 0.0f) * wrL[2][h];
        float s = fmaf(q[r][0], ka.x, rb);
        s = fmaf(q[r][1], ka.y, s);
        s = fmaf(q[r][2], ka.z, s);
        s = fmaf(q[r][3], ka.w, s);
        s = fmaf(q[r][4], kb.x, s);
        s = fminf(s, 85.0f);
        s = ((nw[r] >> lane) & 1ull) ? s : -100.0f;
        float p = __expf(s);
        l[r] += p;
        A[r][0] = fmaf(p, kb.y, A[r][0]);
        A[r][1] = fmaf(p, kb.z, A[r][1]);
        A[r][2] = fmaf(p, kb.w, A[r][2]);
        A[r][3] = fmaf(p, kc.x, A[r][3]);
        A[r][4] = fmaf(p, kc.y, A[r][4]);
      }
    }
    if (t < 15) { ka = nka; kb = nkb; kc = nkc; jz = njz; }
  }
  #pragma unroll
  for (int msk = 1; msk < 64; msk <<= 1) {
    #pragma unroll
    for (int r = 0; r < 4; ++r) {
      l[r] += __shfl_xor(l[r], msk, 64);
      A[r][0] += __shfl_xor(A[r][0], msk, 64);
      A[r][1] += __shfl_xor(A[r][1], msk, 64);
      A[r][2] += __shfl_xor(A[r][2], msk, 64);
      A[r][3] += __shfl_xor(A[r][3], msk, 64);
      A[r][4] += __shfl_xor(A[r][4], msk, 64);
    }
  }

  // ---- per-row contribution -> block-partial pool
  if (lane == 0) {
    float cw[DD] = {0.f, 0.f, 0.f, 0.f, 0.f};
    #pragma unroll
    for (int r = 0; r < 4; ++r) {
      long long grow = (long long)b * NN + chunk * 32 + g * 4 + r;
      float inv = (l[r] > 0.0f) ? 1.0f / l[r] : 0.0f;
      #pragma unroll
      for (int e = 0; e < DD; ++e)
        cw[e] += ldf(feats, grow * DD + e, f32) + A[r][e] * inv;
    }
    #pragma unroll
    for (int e = 0; e < DD; ++e) waveC[g][e] = cw[e];
  }
  __syncthreads();
  if (tid < DD) {
    float s = waveC[0][tid] + waveC[1][tid] + waveC[2][tid] + waveC[3][tid] +
              waveC[4][tid] + waveC[5][tid] + waveC[6][tid] + waveC[7][tid];
    float old = atomicAdd(&pooled[b * DD + tid], s);  // device-scope, coherent
    asm volatile("" :: "v"(old));  // consume return -> add done before cnt
  }
  __syncthreads();  // vmcnt drain: all 5 pooled adds done before counter bump
  if (tid == 0) sLast = (atomicAdd(&cntr[b], 1) == 31) ? 1 : 0;
  __syncthreads();

  // ---- last block for this b runs the pooled MLP (wave-parallel tail)
  if (sLast) {
    if (tid < DD) {
      float pv = __hip_atomic_load(&pooled[b * DD + tid], __ATOMIC_RELAXED,
                                   __HIP_MEMORY_SCOPE_AGENT);
      pM[tid] = pv * (1.0f / 1024.0f);
    }
    __syncthreads();
    if (tid < 128) {
      float acc = ldf(b1, tid, f32);
      #pragma unroll
      for (int d = 0; d < DD; ++d)
        acc = fmaf(pM[d], ldf(w1, d * 128 + tid, f32), acc);
      hL[tid] = fmaxf(acc, 0.0f);
    }
    __syncthreads();
    // 3 outputs, one wave each: 2 products/lane + shuffle reduce
    if (g < 3) {
      float s = hL[lane] * ldf(w2, lane * 3 + g, f32) +
                hL[64 + lane] * ldf(w2, (64 + lane) * 3 + g, f32);
      #pragma unroll
      for (int msk = 1; msk < 64; msk <<= 1) s += __shfl_xor(s, msk, 64);
      if (lane == 0) out[b * 3 + g] = s + ldf(b2, g, f32);
    }
  }
}

// ---------------------------------------------------------------- launch
extern "C" void kernel_launch(void* const* d_in, const int* in_sizes, int n_in,
                              void* d_out, int out_size, void* d_ws, size_t ws_size,
                              hipStream_t stream) {
  const void* adj = d_in[2];
  float* out = (float*)d_out;

  char* w = (char*)d_ws;
  int* gflags = (int*)w;                               // 16 B
  float* pooled = (float*)(w + 64);                    // 320 B
  int* cntr = (int*)(w + 512);                         // 64 B
  const size_t MB2 = (size_t)BB * NN * 16 * sizeof(u64);  // 2 MiB
  u64* adjbits = (u64*)(w + 4096);
  u64* neighbits = (u64*)(w + 4096 + MB2);
  float4* kvg = (float4*)(w + 4096 + 2 * MB2);         // 768 KiB
  float* czg = (float*)(w + 4096 + 2 * MB2 + 786432);  // 64 KiB

  k_pack<<<PACK_BLOCKS + KV_BLOCKS, 256, 0, stream>>>(
      adj, d_in[0], d_in[1], d_in[4], d_in[5], d_in[6], adjbits, kvg, czg,
      gflags, pooled, cntr);
  k_twohop<<<BB * NN / 4, 256, 0, stream>>>(adjbits, neighbits);
  k_attn<<<BB * 32, 512, 0, stream>>>(
      d_in[0], d_in[1], d_in[3], d_in[7], d_in[8], d_in[9], d_in[10], kvg, czg,
      gflags, neighbits, pooled, cntr, d_in[11], d_in[12], d_in[13], d_in[14],
      out);
}